// Round 13
// baseline (469.629 us; speedup 1.0000x reference)
//
#include <hip/hip_runtime.h>
#include <cstdint>
#include <cstddef>

typedef __attribute__((ext_vector_type(8))) short short8;
typedef __attribute__((ext_vector_type(16))) float f32x16;

// ---------- helpers ----------
__device__ __forceinline__ unsigned short f2bf(float x) {
  union { float f; unsigned u; } v; v.f = x;
  unsigned r = (v.u + 0x7FFFu + ((v.u >> 16) & 1u)) >> 16;
  return (unsigned short)r;
}

#define GLOAD16(g, l)                                                    \
  __builtin_amdgcn_global_load_lds(                                      \
      (const __attribute__((address_space(1))) unsigned int*)(g),        \
      (__attribute__((address_space(3))) unsigned int*)(l), 16, 0, 0)

// ---------- f32 -> bf16 conversion (memory-bound) ----------
__global__ __launch_bounds__(256) void cvt_f32_bf16(
    const float* __restrict__ in, unsigned short* __restrict__ out, long n) {
  long i = ((long)blockIdx.x * 256 + threadIdx.x) * 8;
  if (i >= n) return;
  const float4* p = (const float4*)(in + i);
  float4 a = p[0], b = p[1];
  short8 r;
  r[0] = (short)f2bf(a.x); r[1] = (short)f2bf(a.y);
  r[2] = (short)f2bf(a.z); r[3] = (short)f2bf(a.w);
  r[4] = (short)f2bf(b.x); r[5] = (short)f2bf(b.y);
  r[6] = (short)f2bf(b.z); r[7] = (short)f2bf(b.w);
  *(short8*)(out + i) = r;
}

// fused 3-weight conversion (one launch instead of three)
__global__ __launch_bounds__(256) void cvt_w3(
    const float* __restrict__ wa, const float* __restrict__ wb,
    const float* __restrict__ wc, unsigned short* __restrict__ oa,
    unsigned short* __restrict__ ob, unsigned short* __restrict__ oc) {
  int which = blockIdx.x >> 9;             // 512 blocks per weight (D*D/2048)
  long i = ((long)(blockIdx.x & 511) * 256 + threadIdx.x) * 8;
  const float* in = which == 0 ? wa : which == 1 ? wb : wc;
  unsigned short* out = which == 0 ? oa : which == 1 ? ob : oc;
  const float4* p = (const float4*)(in + i);
  float4 a = p[0], b = p[1];
  short8 r;
  r[0] = (short)f2bf(a.x); r[1] = (short)f2bf(a.y);
  r[2] = (short)f2bf(a.z); r[3] = (short)f2bf(a.w);
  r[4] = (short)f2bf(b.x); r[5] = (short)f2bf(b.y);
  r[6] = (short)f2bf(b.z); r[7] = (short)f2bf(b.w);
  *(short8*)(out + i) = r;
}

// sum 64 partials per row, store INVERSE (PV epilogue multiplies)
__global__ __launch_bounds__(256) void reduce_rsum(
    const float* __restrict__ part, float* __restrict__ outr,
    size_t stride, int n) {
  int i = blockIdx.x * 256 + threadIdx.x;
  if (i >= n) return;
  float s = 0.f;
#pragma unroll
  for (int p = 0; p < 64; p++) s += part[(size_t)p * stride + i];
  outr[i] = 1.0f / s;
}

// ---------- gemm_bt256: C[b][m,n] = f( sum_k A[b][m,k]*B[b][n,k] ) -------
// MODE 1: bf16 out (val*scale)
// MODE 2: bf16 out, exp(val*scale); per-wave partial rowsums stored to
//         rs[(bn*4+wn)*rsp + row] (plain stores; r11: cross-XCD atomicAdd
//         ping-pong cost ~47us -- never atomics here)
// MODE 3: f32 out, val * rs[row]  (rs holds INVERSE rowsums)
// 256x256 tile, 8 waves (2M x 4N), BK=64, double-buffered LDS (128 KiB).
// Skeleton (verified r5/r12): prefetch next tile, counted vmcnt(8) so the
// new 8 loads stay in flight across barriers; vmcnt(0) only on last tile;
// two barriers per K-tile; plain C++ compute body (compiler-scheduled
// counted lgkm interleave -- best measured across r2-r12).
// NEW (r13): mfma_f32_32x32x16_bf16 (2382 TF ubench vs 2075 for 16x16x32;
// half the MFMA instruction count, same ds_read count/bytes).
// Fragment reads: row r = base + (lane&31); chunk c = ks*2 + (lane>>5);
// slot = c ^ (r&7)  [r&7 = lane&7, mt-independent].
// C/D layout (m74/m101-verified): col = lane&31,
// row = (reg&3) + 8*(reg>>2) + 4*(lane>>5), reg in [0,16).
// LDS swizzle: 16B slot ^= (row&7); inverse applied on global source.
// Requires M%256==0, N%256==0, K%64==0, gridDim.x%8==0.
template <int MODE>
__global__ __launch_bounds__(512, 2) void gemm_bt256(
    const unsigned short* __restrict__ A, int lda, size_t asb,
    const unsigned short* __restrict__ B, int ldb, size_t bsb,
    void* __restrict__ C, int ldc, size_t csb,
    float* __restrict__ rs, int rss, size_t rsp,
    int nbn, int K, float scale) {
  __shared__ unsigned short As[2][256 * 64];
  __shared__ unsigned short Bs[2][256 * 64];

  A += (size_t)blockIdx.y * asb;
  B += (size_t)blockIdx.y * bsb;
  char* Cb = (char*)C + (size_t)blockIdx.y * csb * (MODE == 3 ? 4 : 2);
  rs += (size_t)blockIdx.y * rss;

  // XCD-aware block swizzle (gridDim.x multiple of 8)
  unsigned bid = blockIdx.x;
  unsigned cpx = gridDim.x >> 3;
  unsigned swz = (bid & 7u) * cpx + (bid >> 3);
  int bm = (int)(swz / (unsigned)nbn);
  int bn = (int)(swz % (unsigned)nbn);
  int m0 = bm * 256, n0 = bn * 256;

  int t512 = threadIdx.x;
  int lane = t512 & 63, wid = t512 >> 6;
  int wm = wid >> 2, wn = wid & 3;           // 2 x 4 wave grid
  int l31 = lane & 31, l5 = lane >> 5;

  // staging: thread t handles 16B chunks at rows srow+{0,64,128,192};
  // LDS slot = t&7 (linear dest), global chunk = slot ^ (srow&7).
  int srow = t512 >> 3;
  int g = (t512 & 7) ^ ((t512 >> 3) & 7);
  const unsigned short* pa = A + (size_t)(m0 + srow) * lda + g * 8;
  const unsigned short* pb = B + (size_t)(n0 + srow) * ldb + g * 8;

  f32x16 acc[4][2] = {};

  const int NT = K >> 6;

#define STAGE(jj, buf)                                                    \
  do {                                                                    \
    int _k0 = (jj) << 6;                                                  \
    _Pragma("unroll") for (int i = 0; i < 4; i++)                         \
        GLOAD16(pa + (size_t)(i * 64) * lda + _k0,                        \
                (char*)As[buf] + i * 8192 + t512 * 16);                   \
    _Pragma("unroll") for (int i = 0; i < 4; i++)                         \
        GLOAD16(pb + (size_t)(i * 64) * ldb + _k0,                        \
                (char*)Bs[buf] + i * 8192 + t512 * 16);                   \
  } while (0)

  // prologue: stage tile 0 into buffer 0
  STAGE(0, 0);

  for (int j = 0; j < NT; ++j) {
    int cur = j & 1;
    // pin all of iteration j-1's reads/MFMAs before the stage below
    __builtin_amdgcn_sched_barrier(0);
    // barrier A: all waves done with buf[cur^1] (tile j-1)
    __builtin_amdgcn_s_barrier();
    if (j + 1 < NT) {
      STAGE(j + 1, cur ^ 1);
      // wait ONLY for tile j's 8 loads; the 8 just issued stay in flight
      asm volatile("s_waitcnt vmcnt(8)" ::: "memory");
    } else {
      asm volatile("s_waitcnt vmcnt(0)" ::: "memory");
    }
    // barrier B: every wave's tile-j loads have landed
    __builtin_amdgcn_s_barrier();

    const char* Ab = (const char*)As[cur];
    const char* Bb = (const char*)Bs[cur];

    // plain reads; compiler interleaves with MFMAs via counted lgkmcnt
    short8 bfv[2][4], afv[4][4];
#pragma unroll
    for (int nt = 0; nt < 2; nt++)
#pragma unroll
      for (int ks = 0; ks < 4; ks++) {
        int r = wn * 64 + nt * 32 + l31;
        int c = (ks * 2 + l5) ^ (r & 7);
        bfv[nt][ks] = *(const short8*)(Bb + r * 128 + c * 16);
      }
#pragma unroll
    for (int mt = 0; mt < 4; mt++)
#pragma unroll
      for (int ks = 0; ks < 4; ks++) {
        int r = wm * 128 + mt * 32 + l31;
        int c = (ks * 2 + l5) ^ (r & 7);
        afv[mt][ks] = *(const short8*)(Ab + r * 128 + c * 16);
      }
#pragma unroll
    for (int ks = 0; ks < 4; ks++)
#pragma unroll
      for (int mt = 0; mt < 4; mt++)
#pragma unroll
        for (int nt = 0; nt < 2; nt++)
          acc[mt][nt] = __builtin_amdgcn_mfma_f32_32x32x16_bf16(
              afv[mt][ks], bfv[nt][ks], acc[mt][nt], 0, 0, 0);
  }
#undef STAGE

  // epilogue; row = m0 + wm*128 + mt*32 + (reg&3)+8*(reg>>2)+4*l5,
  //           col = n0 + wn*64 + nt*32 + l31
  if constexpr (MODE == 2) {
    size_t pslot = (size_t)(bn * 4 + wn) * rsp;
#pragma unroll
    for (int mt = 0; mt < 4; mt++) {
      float sums16[16];
#pragma unroll
      for (int reg = 0; reg < 16; reg++) {
        int row = m0 + wm * 128 + mt * 32 + (reg & 3) + 8 * (reg >> 2) + 4 * l5;
        float e0 = __expf(acc[mt][0][reg] * scale);
        float e1 = __expf(acc[mt][1][reg] * scale);
        ((unsigned short*)Cb)[(size_t)row * ldc + n0 + wn * 64 + l31] = f2bf(e0);
        ((unsigned short*)Cb)[(size_t)row * ldc + n0 + wn * 64 + 32 + l31] =
            f2bf(e1);
        sums16[reg] = e0 + e1;
      }
#pragma unroll
      for (int reg = 0; reg < 16; reg++) {
        float s = sums16[reg];
        s += __shfl_xor(s, 1);
        s += __shfl_xor(s, 2);
        s += __shfl_xor(s, 4);
        s += __shfl_xor(s, 8);
        s += __shfl_xor(s, 16);
        if (l31 == 0) {
          int row =
              m0 + wm * 128 + mt * 32 + (reg & 3) + 8 * (reg >> 2) + 4 * l5;
          rs[pslot + row] = s;
        }
      }
    }
  } else {
#pragma unroll
    for (int mt = 0; mt < 4; mt++) {
#pragma unroll
      for (int reg = 0; reg < 16; reg++) {
        int row = m0 + wm * 128 + mt * 32 + (reg & 3) + 8 * (reg >> 2) + 4 * l5;
        if constexpr (MODE == 1) {
#pragma unroll
          for (int nt = 0; nt < 2; nt++) {
            int col = n0 + wn * 64 + nt * 32 + l31;
            ((unsigned short*)Cb)[(size_t)row * ldc + col] =
                f2bf(acc[mt][nt][reg] * scale);
          }
        } else {
          float iv = rs[row];  // already inverted by reduce_rsum
#pragma unroll
          for (int nt = 0; nt < 2; nt++) {
            int col = n0 + wn * 64 + nt * 32 + l31;
            ((float*)Cb)[(size_t)row * ldc + col] = acc[mt][nt][reg] * iv;
          }
        }
      }
    }
  }
}

// ---------- launcher ----------
extern "C" void kernel_launch(void* const* d_in, const int* in_sizes, int n_in,
                              void* d_out, int out_size, void* d_ws, size_t ws_size,
                              hipStream_t stream) {
  (void)in_sizes; (void)n_in; (void)out_size;
  const float* x  = (const float*)d_in[0];
  const float* Wq = (const float*)d_in[1];
  const float* Wk = (const float*)d_in[2];
  const float* Wv = (const float*)d_in[3];
  float* out = (float*)d_out;

  const int Bn = 4, S = 4096, D = 1024;
  const size_t MS = (size_t)Bn * S;  // 16384
  const float scale = 0.03125f;      // 1/sqrt(1024)

  // ---- workspace layout ----
  char* ws = (char*)d_ws;
  unsigned short* QKb = (unsigned short*)ws; ws += MS * 2048 * 2;        // 64 MiB
  unsigned short* VTb = (unsigned short*)ws; ws += MS * D * 2;           // 32 MiB
  unsigned short* Sreg = (unsigned short*)ws;
  const size_t s4_bytes = (size_t)Bn * S * S * 2;   // 128 MiB
  const size_t s1_bytes = (size_t)S * S * 2;        // 32 MiB
  size_t head = (size_t)(ws - (char*)d_ws);
  bool batched = ws_size >= head + s4_bytes + 16u * 1024 * 1024;
  ws += batched ? s4_bytes : s1_bytes;
  unsigned short* wqkb = (unsigned short*)ws; ws += (size_t)2048 * D * 2;
  unsigned short* wvb  = (unsigned short*)ws; ws += (size_t)D * D * 2;
  float* rpart = (float*)ws; ws += 64 * MS * sizeof(float);              // 4 MiB
  float* rinv  = (float*)ws;                                             // 64 KiB
  unsigned short* xb = Sreg;  // alias: xb dead before any scores write

  // convert inputs to bf16
  cvt_f32_bf16<<<8192, 256, 0, stream>>>(x, xb, (long)MS * D);
  cvt_w3<<<1536, 256, 0, stream>>>(Wq, Wk, Wv, wqkb, wqkb + (size_t)D * D, wvb);

  // QK = x @ [Wq;Wk]^T  (M=16384, N=2048, K=1024)
  gemm_bt256<1><<<dim3(512, 1), 512, 0, stream>>>(
      xb, D, 0, wqkb, D, 0, QKb, 2048, 0, nullptr, 0, 0, 8, D, 1.0f);
  // VT = Wv @ x^T  (M=1024, N=16384, K=1024) -> VTb [1024,16384]
  gemm_bt256<1><<<dim3(256, 1), 512, 0, stream>>>(
      wvb, D, 0, xb, D, 0, VTb, (int)MS, 0, nullptr, 0, 0, 64, D, 1.0f);

  if (batched) {
    // P[b] = exp(Q_b K_b^T * scale); partial rowsums -> rpart
    gemm_bt256<2><<<dim3(256, Bn), 512, 0, stream>>>(
        QKb, 2048, (size_t)S * 2048,
        QKb + 1024, 2048, (size_t)S * 2048,
        Sreg, S, (size_t)S * S, rpart, S, MS, 16, D, scale);
    // inverse rowsums
    reduce_rsum<<<(int)(MS / 256), 256, 0, stream>>>(rpart, rinv, MS, (int)MS);
    // out[b] = (P_b @ V_b) * rinv  (M=4096, N=1024, K=4096)
    gemm_bt256<3><<<dim3(64, Bn), 512, 0, stream>>>(
        Sreg, S, (size_t)S * S,
        VTb, (int)MS, (size_t)S,
        out, D, (size_t)S * D, rinv, S, 0, 4, S, 1.0f);
  } else {
    for (int b = 0; b < Bn; b++) {
      const unsigned short* Qx = QKb + (size_t)b * S * 2048;
      const unsigned short* Kx = Qx + 1024;
      gemm_bt256<2><<<dim3(256, 1), 512, 0, stream>>>(
          Qx, 2048, 0, Kx, 2048, 0, Sreg, S, 0,
          rpart + (size_t)b * S, 0, MS, 16, D, scale);
      reduce_rsum<<<S / 256, 256, 0, stream>>>(
          rpart + (size_t)b * S, rinv + (size_t)b * S, MS, S);
      gemm_bt256<3><<<dim3(64, 1), 512, 0, stream>>>(
          Sreg, S, 0, VTb + (size_t)b * S, (int)MS, 0,
          out + (size_t)b * S * D, D, 0, rinv + (size_t)b * S, 0, 0,
          4, S, 1.0f);
    }
  }
}

// Round 14
// 418.335 us; speedup vs baseline: 1.1226x; 1.1226x over previous
//
#include <hip/hip_runtime.h>
#include <cstdint>
#include <cstddef>

typedef __attribute__((ext_vector_type(8))) short short8;
typedef __attribute__((ext_vector_type(4))) float f32x4;

// ---------- helpers ----------
__device__ __forceinline__ unsigned short f2bf(float x) {
  union { float f; unsigned u; } v; v.f = x;
  unsigned r = (v.u + 0x7FFFu + ((v.u >> 16) & 1u)) >> 16;
  return (unsigned short)r;
}

#define GLOAD16(g, l)                                                    \
  __builtin_amdgcn_global_load_lds(                                      \
      (const __attribute__((address_space(1))) unsigned int*)(g),        \
      (__attribute__((address_space(3))) unsigned int*)(l), 16, 0, 0)

// inline-asm ds_read_b128: order-pinned so counted lgkmcnt is sound.
#define DSR(dst, addrv, imm)                                             \
  asm volatile("ds_read_b128 %0, %1 offset:%c2"                          \
               : "=&v"(dst) : "v"(addrv), "i"(imm))

// ---------- f32 -> bf16 conversion (memory-bound) ----------
__global__ __launch_bounds__(256) void cvt_f32_bf16(
    const float* __restrict__ in, unsigned short* __restrict__ out, long n) {
  long i = ((long)blockIdx.x * 256 + threadIdx.x) * 8;
  if (i >= n) return;
  const float4* p = (const float4*)(in + i);
  float4 a = p[0], b = p[1];
  short8 r;
  r[0] = (short)f2bf(a.x); r[1] = (short)f2bf(a.y);
  r[2] = (short)f2bf(a.z); r[3] = (short)f2bf(a.w);
  r[4] = (short)f2bf(b.x); r[5] = (short)f2bf(b.y);
  r[6] = (short)f2bf(b.z); r[7] = (short)f2bf(b.w);
  *(short8*)(out + i) = r;
}

// fused 3-weight conversion (one launch instead of three)
__global__ __launch_bounds__(256) void cvt_w3(
    const float* __restrict__ wa, const float* __restrict__ wb,
    const float* __restrict__ wc, unsigned short* __restrict__ oa,
    unsigned short* __restrict__ ob, unsigned short* __restrict__ oc) {
  int which = blockIdx.x >> 9;             // 512 blocks per weight (D*D/2048)
  long i = ((long)(blockIdx.x & 511) * 256 + threadIdx.x) * 8;
  const float* in = which == 0 ? wa : which == 1 ? wb : wc;
  unsigned short* out = which == 0 ? oa : which == 1 ? ob : oc;
  const float4* p = (const float4*)(in + i);
  float4 a = p[0], b = p[1];
  short8 r;
  r[0] = (short)f2bf(a.x); r[1] = (short)f2bf(a.y);
  r[2] = (short)f2bf(a.z); r[3] = (short)f2bf(a.w);
  r[4] = (short)f2bf(b.x); r[5] = (short)f2bf(b.y);
  r[6] = (short)f2bf(b.z); r[7] = (short)f2bf(b.w);
  *(short8*)(out + i) = r;
}

// sum 64 partials per row, store INVERSE (PV epilogue multiplies)
__global__ __launch_bounds__(256) void reduce_rsum(
    const float* __restrict__ part, float* __restrict__ outr,
    size_t stride, int n) {
  int i = blockIdx.x * 256 + threadIdx.x;
  if (i >= n) return;
  float s = 0.f;
#pragma unroll
  for (int p = 0; p < 64; p++) s += part[(size_t)p * stride + i];
  outr[i] = 1.0f / s;
}

// ---------- gemm_bt256: C[b][m,n] = f( sum_k A[b][m,k]*B[b][n,k] ) -------
// MODE 1: bf16 out (val*scale)
// MODE 2: bf16 out, exp(val*scale); per-wave partial rowsums stored to
//         rs[(bn*4+wn)*rsp + row] (plain stores; r11: cross-XCD atomicAdd
//         ping-pong cost ~47us -- never atomics here)
// MODE 3: f32 out, val * rs[row]  (rs holds INVERSE rowsums)
// 256x256 tile, 8 waves (2M x 4N), BK=64, double-buffered LDS (128 KiB).
// Staging skeleton (r5/r12-verified): prefetch next tile, counted vmcnt(8);
// vmcnt(0) only on last tile; two barriers per K-tile.
// Compute body (r9/r12-verified): 4 quadrant phases; phase p issues quadrant
// p+1's 4 asm ds_read_b128 then waits lgkmcnt(4) (leaves them in flight),
// sched_barrier(0), setprio(1), 16 MFMA, setprio(0), sched_barrier(0).
// Ledger: pre-loop q0(4)+B(8)=12 -> p0:+4=16,wait4 ; p1/p2:+4=8,wait4 ;
// p3: wait0.  (global_load_lds counts vmcnt, not lgkm.)
// 16x16x32 MFMA kept deliberately: r13 measured the 32x32x16 fragment
// pattern 4-way bank-conflicted under this swizzle (12.6M conflicts, -24%).
// LDS swizzle: 16B slot ^= (row&7); inverse applied on global source.
// Requires M%256==0, N%256==0, K%64==0, gridDim.x%8==0.
template <int MODE>
__global__ __launch_bounds__(512, 2) void gemm_bt256(
    const unsigned short* __restrict__ A, int lda, size_t asb,
    const unsigned short* __restrict__ B, int ldb, size_t bsb,
    void* __restrict__ C, int ldc, size_t csb,
    float* __restrict__ rs, int rss, size_t rsp,
    int nbn, int K, float scale) {
  __shared__ unsigned short As[2][256 * 64];
  __shared__ unsigned short Bs[2][256 * 64];

  A += (size_t)blockIdx.y * asb;
  B += (size_t)blockIdx.y * bsb;
  char* Cb = (char*)C + (size_t)blockIdx.y * csb * (MODE == 3 ? 4 : 2);
  rs += (size_t)blockIdx.y * rss;

  // XCD-aware block swizzle (gridDim.x multiple of 8)
  unsigned bid = blockIdx.x;
  unsigned cpx = gridDim.x >> 3;
  unsigned swz = (bid & 7u) * cpx + (bid >> 3);
  int bm = (int)(swz / (unsigned)nbn);
  int bn = (int)(swz % (unsigned)nbn);
  int m0 = bm * 256, n0 = bn * 256;

  int t512 = threadIdx.x;
  int lane = t512 & 63, wid = t512 >> 6;
  int wm = wid >> 2, wn = wid & 3;           // 2 x 4 wave grid
  int l15 = lane & 15, l4 = lane >> 4;

  // staging: thread t handles 16B chunks at rows srow+{0,64,128,192};
  // LDS slot = t&7 (linear dest), global chunk = slot ^ (srow&7).
  int srow = t512 >> 3;
  int g = (t512 & 7) ^ ((t512 >> 3) & 7);
  const unsigned short* pa = A + (size_t)(m0 + srow) * lda + g * 8;
  const unsigned short* pb = B + (size_t)(n0 + srow) * ldb + g * 8;

  f32x4 acc[8][4] = {};

  const int NT = K >> 6;

#define STAGE(jj, buf)                                                    \
  do {                                                                    \
    int _k0 = (jj) << 6;                                                  \
    _Pragma("unroll") for (int i = 0; i < 4; i++)                         \
        GLOAD16(pa + (size_t)(i * 64) * lda + _k0,                        \
                (char*)As[buf] + i * 8192 + t512 * 16);                   \
    _Pragma("unroll") for (int i = 0; i < 4; i++)                         \
        GLOAD16(pb + (size_t)(i * 64) * ldb + _k0,                        \
                (char*)Bs[buf] + i * 8192 + t512 * 16);                   \
  } while (0)

  // per-ks slot columns and fragment base addresses (mi/ni-independent)
  unsigned c0 = ((unsigned)l4) ^ (unsigned)(l15 & 7);
  unsigned c1 = (4u | (unsigned)l4) ^ (unsigned)(l15 & 7);
  unsigned rowA = (unsigned)(wm * 128 + l15) * 128u;
  unsigned rowB = (unsigned)(wn * 64 + l15) * 128u;

  // prologue: stage tile 0 into buffer 0
  STAGE(0, 0);

  for (int j = 0; j < NT; ++j) {
    int cur = j & 1;
    // pin iteration j-1's body before the stage below
    __builtin_amdgcn_sched_barrier(0);
    // barrier A: all waves done with buf[cur^1] (tile j-1)
    __builtin_amdgcn_s_barrier();
    if (j + 1 < NT) {
      STAGE(j + 1, cur ^ 1);
      // wait ONLY for tile j's 8 loads; the 8 just issued stay in flight
      asm volatile("s_waitcnt vmcnt(8)" ::: "memory");
    } else {
      asm volatile("s_waitcnt vmcnt(0)" ::: "memory");
    }
    // barrier B: every wave's tile-j loads have landed
    __builtin_amdgcn_s_barrier();

    unsigned baseA = (unsigned)(uintptr_t)(
        (__attribute__((address_space(3))) char*)(&As[cur][0]));
    unsigned baseB = (unsigned)(uintptr_t)(
        (__attribute__((address_space(3))) char*)(&Bs[cur][0]));
    unsigned aA0 = baseA + rowA + c0 * 16, aA1 = baseA + rowA + c1 * 16;
    unsigned aB0 = baseB + rowB + c0 * 16, aB1 = baseB + rowB + c1 * 16;

    short8 afq[2][2][2];  // [quadrant parity][m2][ks]
    short8 bfv[4][2];

    // issue quadrant 0 (4 reads) then all B (8 reads): outstanding = 12
    DSR(afq[0][0][0], aA0, 0);
    DSR(afq[0][0][1], aA1, 0);
    DSR(afq[0][1][0], aA0, 2048);
    DSR(afq[0][1][1], aA1, 2048);
#pragma unroll
    for (int ni = 0; ni < 4; ni++) {
      DSR(bfv[ni][0], aB0, ni * 2048);
      DSR(bfv[ni][1], aB1, ni * 2048);
    }

#pragma unroll
    for (int p = 0; p < 4; ++p) {
      if (p < 3) {
        const int mi0 = (p + 1) * 2;
        DSR(afq[(p + 1) & 1][0][0], aA0, mi0 * 2048);
        DSR(afq[(p + 1) & 1][0][1], aA1, mi0 * 2048);
        DSR(afq[(p + 1) & 1][1][0], aA0, (mi0 + 1) * 2048);
        DSR(afq[(p + 1) & 1][1][1], aA1, (mi0 + 1) * 2048);
        // drain everything except the 4 just issued
        asm volatile("s_waitcnt lgkmcnt(4)" ::: "memory");
      } else {
        asm volatile("s_waitcnt lgkmcnt(0)" ::: "memory");
      }
      __builtin_amdgcn_sched_barrier(0);  // rule #18 fence
      __builtin_amdgcn_s_setprio(1);
#pragma unroll
      for (int ks = 0; ks < 2; ks++)
#pragma unroll
        for (int m2 = 0; m2 < 2; m2++) {
          int mi = p * 2 + m2;
#pragma unroll
          for (int ni = 0; ni < 4; ni++)
            acc[mi][ni] = __builtin_amdgcn_mfma_f32_16x16x32_bf16(
                afq[p & 1][m2][ks], bfv[ni][ks], acc[mi][ni], 0, 0, 0);
        }
      __builtin_amdgcn_s_setprio(0);
      __builtin_amdgcn_sched_barrier(0);  // keep MFMA cluster in place
    }
  }
#undef STAGE

  // epilogue; row = m0 + wm*128 + mi*16 + l4*4 + jj, col = n0 + wn*64 + ni*16 + l15
  if constexpr (MODE == 2) {
    float sums[8][4];
#pragma unroll
    for (int mi = 0; mi < 8; mi++)
#pragma unroll
      for (int jj = 0; jj < 4; jj++) sums[mi][jj] = 0.f;
#pragma unroll
    for (int mi = 0; mi < 8; mi++)
#pragma unroll
      for (int ni = 0; ni < 4; ni++)
#pragma unroll
        for (int jj = 0; jj < 4; jj++) {
          int row = m0 + wm * 128 + mi * 16 + l4 * 4 + jj;
          int col = n0 + wn * 64 + ni * 16 + l15;
          float e = __expf(acc[mi][ni][jj] * scale);
          sums[mi][jj] += e;
          ((unsigned short*)Cb)[(size_t)row * ldc + col] = f2bf(e);
        }
    // per-wave partial: reduce 16 col-lanes, ONE plain store per row group
    size_t pslot = (size_t)(bn * 4 + wn) * rsp;
#pragma unroll
    for (int mi = 0; mi < 8; mi++)
#pragma unroll
      for (int jj = 0; jj < 4; jj++) {
        float s = sums[mi][jj];
        s += __shfl_xor(s, 1);
        s += __shfl_xor(s, 2);
        s += __shfl_xor(s, 4);
        s += __shfl_xor(s, 8);
        if (l15 == 0) {
          int row = m0 + wm * 128 + mi * 16 + l4 * 4 + jj;
          rs[pslot + row] = s;
        }
      }
  } else {
#pragma unroll
    for (int mi = 0; mi < 8; mi++) {
      float inv[4];
      if constexpr (MODE == 3) {
#pragma unroll
        for (int jj = 0; jj < 4; jj++) {
          int row = m0 + wm * 128 + mi * 16 + l4 * 4 + jj;
          inv[jj] = rs[row];  // already inverted by reduce_rsum
        }
      }
#pragma unroll
      for (int ni = 0; ni < 4; ni++)
#pragma unroll
        for (int jj = 0; jj < 4; jj++) {
          int row = m0 + wm * 128 + mi * 16 + l4 * 4 + jj;
          int col = n0 + wn * 64 + ni * 16 + l15;
          float val = acc[mi][ni][jj];
          if constexpr (MODE == 1)
            ((unsigned short*)Cb)[(size_t)row * ldc + col] = f2bf(val * scale);
          else
            ((float*)Cb)[(size_t)row * ldc + col] = val * inv[jj];
        }
    }
  }
}

// ---------- launcher ----------
extern "C" void kernel_launch(void* const* d_in, const int* in_sizes, int n_in,
                              void* d_out, int out_size, void* d_ws, size_t ws_size,
                              hipStream_t stream) {
  (void)in_sizes; (void)n_in; (void)out_size;
  const float* x  = (const float*)d_in[0];
  const float* Wq = (const float*)d_in[1];
  const float* Wk = (const float*)d_in[2];
  const float* Wv = (const float*)d_in[3];
  float* out = (float*)d_out;

  const int Bn = 4, S = 4096, D = 1024;
  const size_t MS = (size_t)Bn * S;  // 16384
  const float scale = 0.03125f;      // 1/sqrt(1024)

  // ---- workspace layout ----
  char* ws = (char*)d_ws;
  unsigned short* QKb = (unsigned short*)ws; ws += MS * 2048 * 2;        // 64 MiB
  unsigned short* VTb = (unsigned short*)ws; ws += MS * D * 2;           // 32 MiB
  unsigned short* Sreg = (unsigned short*)ws;
  const size_t s4_bytes = (size_t)Bn * S * S * 2;   // 128 MiB
  const size_t s1_bytes = (size_t)S * S * 2;        // 32 MiB
  size_t head = (size_t)(ws - (char*)d_ws);
  bool batched = ws_size >= head + s4_bytes + 16u * 1024 * 1024;
  ws += batched ? s4_bytes : s1_bytes;
  unsigned short* wqkb = (unsigned short*)ws; ws += (size_t)2048 * D * 2;
  unsigned short* wvb  = (unsigned short*)ws; ws += (size_t)D * D * 2;
  float* rpart = (float*)ws; ws += 64 * MS * sizeof(float);              // 4 MiB
  float* rinv  = (float*)ws;                                             // 64 KiB
  unsigned short* xb = Sreg;  // alias: xb dead before any scores write

  // convert inputs to bf16
  cvt_f32_bf16<<<8192, 256, 0, stream>>>(x, xb, (long)MS * D);
  cvt_w3<<<1536, 256, 0, stream>>>(Wq, Wk, Wv, wqkb, wqkb + (size_t)D * D, wvb);

  // QK = x @ [Wq;Wk]^T  (M=16384, N=2048, K=1024)
  gemm_bt256<1><<<dim3(512, 1), 512, 0, stream>>>(
      xb, D, 0, wqkb, D, 0, QKb, 2048, 0, nullptr, 0, 0, 8, D, 1.0f);
  // VT = Wv @ x^T  (M=1024, N=16384, K=1024) -> VTb [1024,16384]
  gemm_bt256<1><<<dim3(256, 1), 512, 0, stream>>>(
      wvb, D, 0, xb, D, 0, VTb, (int)MS, 0, nullptr, 0, 0, 64, D, 1.0f);

  if (batched) {
    // P[b] = exp(Q_b K_b^T * scale); partial rowsums -> rpart
    gemm_bt256<2><<<dim3(256, Bn), 512, 0, stream>>>(
        QKb, 2048, (size_t)S * 2048,
        QKb + 1024, 2048, (size_t)S * 2048,
        Sreg, S, (size_t)S * S, rpart, S, MS, 16, D, scale);
    // inverse rowsums
    reduce_rsum<<<(int)(MS / 256), 256, 0, stream>>>(rpart, rinv, MS, (int)MS);
    // out[b] = (P_b @ V_b) * rinv  (M=4096, N=1024, K=4096)
    gemm_bt256<3><<<dim3(64, Bn), 512, 0, stream>>>(
        Sreg, S, (size_t)S * S,
        VTb, (int)MS, (size_t)S,
        out, D, (size_t)S * D, rinv, S, 0, 4, S, 1.0f);
  } else {
    for (int b = 0; b < Bn; b++) {
      const unsigned short* Qx = QKb + (size_t)b * S * 2048;
      const unsigned short* Kx = Qx + 1024;
      gemm_bt256<2><<<dim3(256, 1), 512, 0, stream>>>(
          Qx, 2048, 0, Kx, 2048, 0, Sreg, S, 0,
          rpart + (size_t)b * S, 0, MS, 16, D, scale);
      reduce_rsum<<<S / 256, 256, 0, stream>>>(
          rpart + (size_t)b * S, rinv + (size_t)b * S, MS, S);
      gemm_bt256<3><<<dim3(64, 1), 512, 0, stream>>>(
          Sreg, S, 0, VTb + (size_t)b * S, (int)MS, 0,
          out + (size_t)b * S * D, D, 0, rinv + (size_t)b * S, 0, 0,
          4, S, 1.0f);
    }
  }
}

// Round 15
// 406.838 us; speedup vs baseline: 1.1543x; 1.0283x over previous
//
#include <hip/hip_runtime.h>
#include <cstdint>
#include <cstddef>

typedef __attribute__((ext_vector_type(8))) short short8;
typedef __attribute__((ext_vector_type(4))) float f32x4;

// ---------- helpers ----------
__device__ __forceinline__ unsigned short f2bf(float x) {
  union { float f; unsigned u; } v; v.f = x;
  unsigned r = (v.u + 0x7FFFu + ((v.u >> 16) & 1u)) >> 16;
  return (unsigned short)r;
}

#define GLOAD16(g, l)                                                    \
  __builtin_amdgcn_global_load_lds(                                      \
      (const __attribute__((address_space(1))) unsigned int*)(g),        \
      (__attribute__((address_space(3))) unsigned int*)(l), 16, 0, 0)

// inline-asm ds_read_b128: order-pinned so counted lgkmcnt is sound.
#define DSR(dst, addrv, imm)                                             \
  asm volatile("ds_read_b128 %0, %1 offset:%c2"                          \
               : "=&v"(dst) : "v"(addrv), "i"(imm))

// ---------- f32 -> bf16 conversion (memory-bound) ----------
__global__ __launch_bounds__(256) void cvt_f32_bf16(
    const float* __restrict__ in, unsigned short* __restrict__ out, long n) {
  long i = ((long)blockIdx.x * 256 + threadIdx.x) * 8;
  if (i >= n) return;
  const float4* p = (const float4*)(in + i);
  float4 a = p[0], b = p[1];
  short8 r;
  r[0] = (short)f2bf(a.x); r[1] = (short)f2bf(a.y);
  r[2] = (short)f2bf(a.z); r[3] = (short)f2bf(a.w);
  r[4] = (short)f2bf(b.x); r[5] = (short)f2bf(b.y);
  r[6] = (short)f2bf(b.z); r[7] = (short)f2bf(b.w);
  *(short8*)(out + i) = r;
}

// ---------- transpose + convert: out[i][o] = bf16(in[o][i]), 1024x1024 ---
// grid 512: blocks 0-255 -> (wq,oq), 256-511 -> (wk,ok). 64x64 LDS tiles.
__global__ __launch_bounds__(256) void transpose_cvt2(
    const float* __restrict__ wq, const float* __restrict__ wk,
    unsigned short* __restrict__ oq, unsigned short* __restrict__ ok) {
  __shared__ float tile[64][65];
  int b = blockIdx.x;
  const float* in = (b & 256) ? wk : wq;
  unsigned short* out = (b & 256) ? ok : oq;
  int tb = b & 255;
  int O0 = (tb >> 4) * 64;  // input row block (o)
  int I0 = (tb & 15) * 64;  // input col block (i)
  int t = threadIdx.x;
  int r0 = t >> 6, c = t & 63;
#pragma unroll
  for (int r = 0; r < 16; r++) {
    int row = r * 4 + r0;
    tile[row][c] = in[(size_t)(O0 + row) * 1024 + I0 + c];
  }
  __syncthreads();
#pragma unroll
  for (int r = 0; r < 16; r++) {
    int irow = r * 4 + r0;
    out[(size_t)(I0 + irow) * 1024 + O0 + c] = f2bf(tile[c][irow]);
  }
}

// sum 64 partials per row, store INVERSE (PV epilogue multiplies)
__global__ __launch_bounds__(256) void reduce_rsum(
    const float* __restrict__ part, float* __restrict__ outr,
    size_t stride, int n) {
  int i = blockIdx.x * 256 + threadIdx.x;
  if (i >= n) return;
  float s = 0.f;
#pragma unroll
  for (int p = 0; p < 64; p++) s += part[(size_t)p * stride + i];
  outr[i] = 1.0f / s;
}

// ---------- gemm128: C[m,n] = bf16( scale * sum_k A[m,k]*B[n,k] ) -------
// r1/r2-verified 128x128 tile, 4 waves, BK=64 (0 bank conflicts measured).
// Used for the tiny M^T = Wk^T-x-Wq weight GEMM (64 blocks, ~6us) where the
// 256^2 kernel would waste a 41us round at 6% utilization.
__global__ __launch_bounds__(256) void gemm128(
    const unsigned short* __restrict__ A, int lda,
    const unsigned short* __restrict__ B, int ldb,
    unsigned short* __restrict__ C, int ldc,
    int nbn, int K, float scale) {
  __shared__ unsigned short As[128 * 64];
  __shared__ unsigned short Bs[128 * 64];

  unsigned bid = blockIdx.x;
  unsigned cpx = gridDim.x >> 3;
  unsigned swz = (bid & 7u) * cpx + (bid >> 3);
  int bm = (int)(swz / (unsigned)nbn);
  int bn = (int)(swz % (unsigned)nbn);
  int m0 = bm * 128, n0 = bn * 128;

  int t = threadIdx.x;
  int lane = t & 63, wid = t >> 6;
  int wm = wid >> 1, wn = wid & 1;
  int l15 = lane & 15, l4 = lane >> 4;

  int srow = t >> 3;
  int g = (t & 7) ^ ((t >> 3) & 7);
  const unsigned short* pa = A + (size_t)(m0 + srow) * lda + g * 8;
  const unsigned short* pb = B + (size_t)(n0 + srow) * ldb + g * 8;

  f32x4 acc[4][4] = {};

  for (int k0 = 0; k0 < K; k0 += 64) {
    __syncthreads();
#pragma unroll
    for (int i = 0; i < 4; i++) {
      GLOAD16(pa + (size_t)(32 * i) * lda + k0,
              (char*)As + (size_t)(i * 256 + wid * 64) * 16);
      GLOAD16(pb + (size_t)(32 * i) * ldb + k0,
              (char*)Bs + (size_t)(i * 256 + wid * 64) * 16);
    }
    __syncthreads();
#pragma unroll
    for (int ks = 0; ks < 2; ks++) {
      short8 af[4], bfr[4];
#pragma unroll
      for (int mi = 0; mi < 4; mi++) {
        int r = wm * 64 + mi * 16 + l15;
        int c = ((ks << 2) | l4) ^ (r & 7);
        af[mi] = *(const short8*)((const char*)As + r * 128 + c * 16);
      }
#pragma unroll
      for (int ni = 0; ni < 4; ni++) {
        int r = wn * 64 + ni * 16 + l15;
        int c = ((ks << 2) | l4) ^ (r & 7);
        bfr[ni] = *(const short8*)((const char*)Bs + r * 128 + c * 16);
      }
#pragma unroll
      for (int mi = 0; mi < 4; mi++)
#pragma unroll
        for (int ni = 0; ni < 4; ni++)
          acc[mi][ni] = __builtin_amdgcn_mfma_f32_16x16x32_bf16(
              af[mi], bfr[ni], acc[mi][ni], 0, 0, 0);
    }
  }

#pragma unroll
  for (int mi = 0; mi < 4; mi++)
#pragma unroll
    for (int ni = 0; ni < 4; ni++)
#pragma unroll
      for (int j = 0; j < 4; j++) {
        int row = m0 + wm * 64 + mi * 16 + l4 * 4 + j;
        int col = n0 + wn * 64 + ni * 16 + l15;
        C[(size_t)row * ldc + col] = f2bf(acc[mi][ni][j] * scale);
      }
}

// ---------- gemm_bt256: C[b][m,n] = f( sum_k A[b][m,k]*B[b][n,k] ) -------
// MODE 1: bf16 out (val*scale)
// MODE 2: bf16 out, exp(val*scale); per-wave partial rowsums stored to
//         rs[(bn*4+wn)*rsp + row] (plain stores; r11: cross-XCD atomicAdd
//         ping-pong cost ~47us -- never atomics here)
// MODE 3: f32 out, val * rs[row]  (rs holds INVERSE rowsums)
// 256x256 tile, 8 waves (2M x 4N), BK=64, double-buffered LDS (128 KiB).
// Staging skeleton (r5/r12/r14-verified): prefetch next tile, counted
// vmcnt(8); vmcnt(0) only on last tile; two barriers per K-tile.
// Compute body (r9/r12/r14-verified): 4 quadrant phases with asm-pinned
// ds_read_b128 + counted lgkmcnt(4), setprio around MFMA clusters.
// 16x16x32 MFMA kept (r13: 32x32 fragment pattern 4-way conflicts here).
// LDS swizzle: 16B slot ^= (row&7); inverse applied on global source.
// Requires M%256==0, N%256==0, K%64==0, gridDim.x%8==0.
template <int MODE>
__global__ __launch_bounds__(512, 2) void gemm_bt256(
    const unsigned short* __restrict__ A, int lda, size_t asb,
    const unsigned short* __restrict__ B, int ldb, size_t bsb,
    void* __restrict__ C, int ldc, size_t csb,
    float* __restrict__ rs, int rss, size_t rsp,
    int nbn, int K, float scale) {
  __shared__ unsigned short As[2][256 * 64];
  __shared__ unsigned short Bs[2][256 * 64];

  A += (size_t)blockIdx.y * asb;
  B += (size_t)blockIdx.y * bsb;
  char* Cb = (char*)C + (size_t)blockIdx.y * csb * (MODE == 3 ? 4 : 2);
  rs += (size_t)blockIdx.y * rss;

  // XCD-aware block swizzle (gridDim.x multiple of 8)
  unsigned bid = blockIdx.x;
  unsigned cpx = gridDim.x >> 3;
  unsigned swz = (bid & 7u) * cpx + (bid >> 3);
  int bm = (int)(swz / (unsigned)nbn);
  int bn = (int)(swz % (unsigned)nbn);
  int m0 = bm * 256, n0 = bn * 256;

  int t512 = threadIdx.x;
  int lane = t512 & 63, wid = t512 >> 6;
  int wm = wid >> 2, wn = wid & 3;           // 2 x 4 wave grid
  int l15 = lane & 15, l4 = lane >> 4;

  // staging: thread t handles 16B chunks at rows srow+{0,64,128,192};
  // LDS slot = t&7 (linear dest), global chunk = slot ^ (srow&7).
  int srow = t512 >> 3;
  int g = (t512 & 7) ^ ((t512 >> 3) & 7);
  const unsigned short* pa = A + (size_t)(m0 + srow) * lda + g * 8;
  const unsigned short* pb = B + (size_t)(n0 + srow) * ldb + g * 8;

  f32x4 acc[8][4] = {};

  const int NT = K >> 6;

#define STAGE(jj, buf)                                                    \
  do {                                                                    \
    int _k0 = (jj) << 6;                                                  \
    _Pragma("unroll") for (int i = 0; i < 4; i++)                         \
        GLOAD16(pa + (size_t)(i * 64) * lda + _k0,                        \
                (char*)As[buf] + i * 8192 + t512 * 16);                   \
    _Pragma("unroll") for (int i = 0; i < 4; i++)                         \
        GLOAD16(pb + (size_t)(i * 64) * ldb + _k0,                        \
                (char*)Bs[buf] + i * 8192 + t512 * 16);                   \
  } while (0)

  // per-ks slot columns and fragment base addresses (mi/ni-independent)
  unsigned c0 = ((unsigned)l4) ^ (unsigned)(l15 & 7);
  unsigned c1 = (4u | (unsigned)l4) ^ (unsigned)(l15 & 7);
  unsigned rowA = (unsigned)(wm * 128 + l15) * 128u;
  unsigned rowB = (unsigned)(wn * 64 + l15) * 128u;

  // prologue: stage tile 0 into buffer 0
  STAGE(0, 0);

  for (int j = 0; j < NT; ++j) {
    int cur = j & 1;
    // pin iteration j-1's body before the stage below
    __builtin_amdgcn_sched_barrier(0);
    // barrier A: all waves done with buf[cur^1] (tile j-1)
    __builtin_amdgcn_s_barrier();
    if (j + 1 < NT) {
      STAGE(j + 1, cur ^ 1);
      // wait ONLY for tile j's 8 loads; the 8 just issued stay in flight
      asm volatile("s_waitcnt vmcnt(8)" ::: "memory");
    } else {
      asm volatile("s_waitcnt vmcnt(0)" ::: "memory");
    }
    // barrier B: every wave's tile-j loads have landed
    __builtin_amdgcn_s_barrier();

    unsigned baseA = (unsigned)(uintptr_t)(
        (__attribute__((address_space(3))) char*)(&As[cur][0]));
    unsigned baseB = (unsigned)(uintptr_t)(
        (__attribute__((address_space(3))) char*)(&Bs[cur][0]));
    unsigned aA0 = baseA + rowA + c0 * 16, aA1 = baseA + rowA + c1 * 16;
    unsigned aB0 = baseB + rowB + c0 * 16, aB1 = baseB + rowB + c1 * 16;

    short8 afq[2][2][2];  // [quadrant parity][m2][ks]
    short8 bfv[4][2];

    // issue quadrant 0 (4 reads) then all B (8 reads): outstanding = 12
    DSR(afq[0][0][0], aA0, 0);
    DSR(afq[0][0][1], aA1, 0);
    DSR(afq[0][1][0], aA0, 2048);
    DSR(afq[0][1][1], aA1, 2048);
#pragma unroll
    for (int ni = 0; ni < 4; ni++) {
      DSR(bfv[ni][0], aB0, ni * 2048);
      DSR(bfv[ni][1], aB1, ni * 2048);
    }

#pragma unroll
    for (int p = 0; p < 4; ++p) {
      if (p < 3) {
        const int mi0 = (p + 1) * 2;
        DSR(afq[(p + 1) & 1][0][0], aA0, mi0 * 2048);
        DSR(afq[(p + 1) & 1][0][1], aA1, mi0 * 2048);
        DSR(afq[(p + 1) & 1][1][0], aA0, (mi0 + 1) * 2048);
        DSR(afq[(p + 1) & 1][1][1], aA1, (mi0 + 1) * 2048);
        // drain everything except the 4 just issued
        asm volatile("s_waitcnt lgkmcnt(4)" ::: "memory");
      } else {
        asm volatile("s_waitcnt lgkmcnt(0)" ::: "memory");
      }
      __builtin_amdgcn_sched_barrier(0);  // rule #18 fence
      __builtin_amdgcn_s_setprio(1);
#pragma unroll
      for (int ks = 0; ks < 2; ks++)
#pragma unroll
        for (int m2 = 0; m2 < 2; m2++) {
          int mi = p * 2 + m2;
#pragma unroll
          for (int ni = 0; ni < 4; ni++)
            acc[mi][ni] = __builtin_amdgcn_mfma_f32_16x16x32_bf16(
                afq[p & 1][m2][ks], bfv[ni][ks], acc[mi][ni], 0, 0, 0);
        }
      __builtin_amdgcn_s_setprio(0);
      __builtin_amdgcn_sched_barrier(0);  // keep MFMA cluster in place
    }
  }
#undef STAGE

  // epilogue; row = m0 + wm*128 + mi*16 + l4*4 + jj, col = n0 + wn*64 + ni*16 + l15
  if constexpr (MODE == 2) {
    float sums[8][4];
#pragma unroll
    for (int mi = 0; mi < 8; mi++)
#pragma unroll
      for (int jj = 0; jj < 4; jj++) sums[mi][jj] = 0.f;
#pragma unroll
    for (int mi = 0; mi < 8; mi++)
#pragma unroll
      for (int ni = 0; ni < 4; ni++)
#pragma unroll
        for (int jj = 0; jj < 4; jj++) {
          int row = m0 + wm * 128 + mi * 16 + l4 * 4 + jj;
          int col = n0 + wn * 64 + ni * 16 + l15;
          float e = __expf(acc[mi][ni][jj] * scale);
          sums[mi][jj] += e;
          ((unsigned short*)Cb)[(size_t)row * ldc + col] = f2bf(e);
        }
    // per-wave partial: reduce 16 col-lanes, ONE plain store per row group
    size_t pslot = (size_t)(bn * 4 + wn) * rsp;
#pragma unroll
    for (int mi = 0; mi < 8; mi++)
#pragma unroll
      for (int jj = 0; jj < 4; jj++) {
        float s = sums[mi][jj];
        s += __shfl_xor(s, 1);
        s += __shfl_xor(s, 2);
        s += __shfl_xor(s, 4);
        s += __shfl_xor(s, 8);
        if (l15 == 0) {
          int row = m0 + wm * 128 + mi * 16 + l4 * 4 + jj;
          rs[pslot + row] = s;
        }
      }
  } else {
#pragma unroll
    for (int mi = 0; mi < 8; mi++) {
      float inv[4];
      if constexpr (MODE == 3) {
#pragma unroll
        for (int jj = 0; jj < 4; jj++) {
          int row = m0 + wm * 128 + mi * 16 + l4 * 4 + jj;
          inv[jj] = rs[row];  // already inverted by reduce_rsum
        }
      }
#pragma unroll
      for (int ni = 0; ni < 4; ni++)
#pragma unroll
        for (int jj = 0; jj < 4; jj++) {
          int row = m0 + wm * 128 + mi * 16 + l4 * 4 + jj;
          int col = n0 + wn * 64 + ni * 16 + l15;
          float val = acc[mi][ni][jj];
          if constexpr (MODE == 1)
            ((unsigned short*)Cb)[(size_t)row * ldc + col] = f2bf(val * scale);
          else
            ((float*)Cb)[(size_t)row * ldc + col] = val * inv[jj];
        }
    }
  }
}

// ---------- launcher ----------
// Pipeline (associativity: scores = x (Wq^T Wk) x^T):
//   xb = bf16(x); wvb = bf16(Wv); wqT/wkT = bf16 transposes of Wq/Wk
//   MT = gemm128(wkT, wqT)            [MT[j,i] = sum_o Wq[o,i]Wk[o,j]^T]
//   VT = gemm256(wvb, xb)             [V^T, 1024 x 16384]
//   xM = gemm256(xb, MT)              [xM[q,j] = sum_i x[q,i]M[i,j]]
//   P  = exp(gemm256(xM, xb) * scale) + partial rowsums
//   out = gemm256(P, VT-slice) * rinv
extern "C" void kernel_launch(void* const* d_in, const int* in_sizes, int n_in,
                              void* d_out, int out_size, void* d_ws, size_t ws_size,
                              hipStream_t stream) {
  (void)in_sizes; (void)n_in; (void)out_size;
  const float* x  = (const float*)d_in[0];
  const float* Wq = (const float*)d_in[1];
  const float* Wk = (const float*)d_in[2];
  const float* Wv = (const float*)d_in[3];
  float* out = (float*)d_out;

  const int Bn = 4, S = 4096, D = 1024;
  const size_t MS = (size_t)Bn * S;  // 16384
  const float scale = 0.03125f;      // 1/sqrt(1024)

  // ---- workspace layout ----
  char* ws = (char*)d_ws;
  unsigned short* xb  = (unsigned short*)ws; ws += MS * D * 2;   // 32 MiB
  unsigned short* xMb = (unsigned short*)ws; ws += MS * D * 2;   // 32 MiB
  unsigned short* VTb = (unsigned short*)ws; ws += MS * D * 2;   // 32 MiB
  unsigned short* Sreg = (unsigned short*)ws;
  const size_t s4_bytes = (size_t)Bn * S * S * 2;   // 128 MiB
  const size_t s1_bytes = (size_t)S * S * 2;        // 32 MiB
  size_t head = (size_t)(ws - (char*)d_ws);
  bool batched = ws_size >= head + s4_bytes + 16u * 1024 * 1024;
  ws += batched ? s4_bytes : s1_bytes;
  unsigned short* wqT = (unsigned short*)ws; ws += (size_t)D * D * 2;  // 2 MiB
  unsigned short* wkT = (unsigned short*)ws; ws += (size_t)D * D * 2;
  unsigned short* MTb = (unsigned short*)ws; ws += (size_t)D * D * 2;
  unsigned short* wvb = (unsigned short*)ws; ws += (size_t)D * D * 2;
  float* rpart = (float*)ws; ws += 64 * MS * sizeof(float);            // 4 MiB
  float* rinv  = (float*)ws;                                           // 64 KiB

  // convert inputs to bf16
  cvt_f32_bf16<<<8192, 256, 0, stream>>>(x, xb, (long)MS * D);
  cvt_f32_bf16<<<512, 256, 0, stream>>>(Wv, wvb, (long)D * D);
  transpose_cvt2<<<512, 256, 0, stream>>>(Wq, Wk, wqT, wkT);

  // MT[j,i] = sum_o Wk[o,j]Wq[o,i]  (M=N=1024, K=1024; 64 blocks, ~6us)
  gemm128<<<64, 256, 0, stream>>>(wkT, D, wqT, D, MTb, D, 8, D, 1.0f);

  // VT = Wv @ x^T  (M=1024, N=16384, K=1024) -> VTb [1024,16384]
  gemm_bt256<1><<<dim3(256, 1), 512, 0, stream>>>(
      wvb, D, 0, xb, D, 0, VTb, (int)MS, 0, nullptr, 0, 0, 64, D, 1.0f);

  // xM[q,j] = sum_i x[q,i] MT[j,i]  (M=16384, N=1024, K=1024)
  gemm_bt256<1><<<dim3(256, 1), 512, 0, stream>>>(
      xb, D, 0, MTb, D, 0, xMb, D, 0, nullptr, 0, 0, 4, D, 1.0f);

  if (batched) {
    // P[b] = exp(xM_b x_b^T * scale); partial rowsums -> rpart
    gemm_bt256<2><<<dim3(256, Bn), 512, 0, stream>>>(
        xMb, D, (size_t)S * D,
        xb, D, (size_t)S * D,
        Sreg, S, (size_t)S * S, rpart, S, MS, 16, D, scale);
    // inverse rowsums
    reduce_rsum<<<(int)(MS / 256), 256, 0, stream>>>(rpart, rinv, MS, (int)MS);
    // out[b] = (P_b @ V_b) * rinv  (M=4096, N=1024, K=4096)
    gemm_bt256<3><<<dim3(64, Bn), 512, 0, stream>>>(
        Sreg, S, (size_t)S * S,
        VTb, (int)MS, (size_t)S,
        out, D, (size_t)S * D, rinv, S, 0, 4, S, 1.0f);
  } else {
    for (int b = 0; b < Bn; b++) {
      gemm_bt256<2><<<dim3(256, 1), 512, 0, stream>>>(
          xMb + (size_t)b * S * D, D, 0,
          xb + (size_t)b * S * D, D, 0,
          Sreg, S, 0, rpart + (size_t)b * S, 0, MS, 16, D, scale);
      reduce_rsum<<<S / 256, 256, 0, stream>>>(
          rpart + (size_t)b * S, rinv + (size_t)b * S, MS, S);
      gemm_bt256<3><<<dim3(64, 1), 512, 0, stream>>>(
          Sreg, S, 0, VTb + (size_t)b * S, (int)MS, 0,
          out + (size_t)b * S * D, D, 0, rinv + (size_t)b * S, 0, 0,
          4, S, 1.0f);
    }
  }
}

// Round 16
// 400.952 us; speedup vs baseline: 1.1713x; 1.0147x over previous
//
#include <hip/hip_runtime.h>
#include <cstdint>
#include <cstddef>

typedef __attribute__((ext_vector_type(8))) short short8;
typedef __attribute__((ext_vector_type(4))) float f32x4;

// ---------- helpers ----------
__device__ __forceinline__ unsigned short f2bf(float x) {
  union { float f; unsigned u; } v; v.f = x;
  unsigned r = (v.u + 0x7FFFu + ((v.u >> 16) & 1u)) >> 16;
  return (unsigned short)r;
}

#define GLOAD16(g, l)                                                    \
  __builtin_amdgcn_global_load_lds(                                      \
      (const __attribute__((address_space(1))) unsigned int*)(g),        \
      (__attribute__((address_space(3))) unsigned int*)(l), 16, 0, 0)

// inline-asm ds_read_b128: order-pinned so counted lgkmcnt is sound.
#define DSR(dst, addrv, imm)                                             \
  asm volatile("ds_read_b128 %0, %1 offset:%c2"                          \
               : "=&v"(dst) : "v"(addrv), "i"(imm))

// ---------- merged conversion front-end (one launch) ----------
// blocks [0,8192)    : cvt f32->bf16 of x        (16384x1024)
// blocks [8192,8704) : transpose+cvt Wq/Wk -> wqT/wkT (64x64 LDS tiles)
// blocks [8704,9216) : cvt f32->bf16 of Wv       (1024x1024)
__global__ __launch_bounds__(256) void cvt_all(
    const float* __restrict__ x, unsigned short* __restrict__ xb,
    const float* __restrict__ wq, const float* __restrict__ wk,
    unsigned short* __restrict__ wqT, unsigned short* __restrict__ wkT,
    const float* __restrict__ wv, unsigned short* __restrict__ wvb) {
  __shared__ float tile[64][65];
  int b = blockIdx.x;
  int t = threadIdx.x;
  if (b < 8192) {
    long i = ((long)b * 256 + t) * 8;
    const float4* p = (const float4*)(x + i);
    float4 a = p[0], c = p[1];
    short8 r;
    r[0] = (short)f2bf(a.x); r[1] = (short)f2bf(a.y);
    r[2] = (short)f2bf(a.z); r[3] = (short)f2bf(a.w);
    r[4] = (short)f2bf(c.x); r[5] = (short)f2bf(c.y);
    r[6] = (short)f2bf(c.z); r[7] = (short)f2bf(c.w);
    *(short8*)(xb + i) = r;
  } else if (b < 8704) {
    int tb = b - 8192;
    const float* in = (tb & 256) ? wk : wq;
    unsigned short* out = (tb & 256) ? wkT : wqT;
    int tb2 = tb & 255;
    int O0 = (tb2 >> 4) * 64;  // input row block (o)
    int I0 = (tb2 & 15) * 64;  // input col block (i)
    int r0 = t >> 6, c = t & 63;
#pragma unroll
    for (int r = 0; r < 16; r++) {
      int row = r * 4 + r0;
      tile[row][c] = in[(size_t)(O0 + row) * 1024 + I0 + c];
    }
    __syncthreads();
#pragma unroll
    for (int r = 0; r < 16; r++) {
      int irow = r * 4 + r0;
      out[(size_t)(I0 + irow) * 1024 + O0 + c] = f2bf(tile[c][irow]);
    }
  } else {
    long i = ((long)(b - 8704) * 256 + t) * 8;
    const float4* p = (const float4*)(wv + i);
    float4 a = p[0], c = p[1];
    short8 r;
    r[0] = (short)f2bf(a.x); r[1] = (short)f2bf(a.y);
    r[2] = (short)f2bf(a.z); r[3] = (short)f2bf(a.w);
    r[4] = (short)f2bf(c.x); r[5] = (short)f2bf(c.y);
    r[6] = (short)f2bf(c.z); r[7] = (short)f2bf(c.w);
    *(short8*)(wvb + i) = r;
  }
}

// sum 64 partials per row, store INVERSE (PV epilogue multiplies)
__global__ __launch_bounds__(256) void reduce_rsum(
    const float* __restrict__ part, float* __restrict__ outr,
    size_t stride, int n) {
  int i = blockIdx.x * 256 + threadIdx.x;
  if (i >= n) return;
  float s = 0.f;
#pragma unroll
  for (int p = 0; p < 64; p++) s += part[(size_t)p * stride + i];
  outr[i] = 1.0f / s;
}

// ---------- gemm128: C[m,n] = bf16( scale * sum_k A[m,k]*B[n,k] ) -------
// r1/r2-verified 128x128 tile, 4 waves, BK=64. Used for the tiny
// M^T weight GEMM (64 blocks) where the 256^2 kernel would waste a round.
__global__ __launch_bounds__(256) void gemm128(
    const unsigned short* __restrict__ A, int lda,
    const unsigned short* __restrict__ B, int ldb,
    unsigned short* __restrict__ C, int ldc,
    int nbn, int K, float scale) {
  __shared__ unsigned short As[128 * 64];
  __shared__ unsigned short Bs[128 * 64];

  unsigned bid = blockIdx.x;
  unsigned cpx = gridDim.x >> 3;
  unsigned swz = (bid & 7u) * cpx + (bid >> 3);
  int bm = (int)(swz / (unsigned)nbn);
  int bn = (int)(swz % (unsigned)nbn);
  int m0 = bm * 128, n0 = bn * 128;

  int t = threadIdx.x;
  int lane = t & 63, wid = t >> 6;
  int wm = wid >> 1, wn = wid & 1;
  int l15 = lane & 15, l4 = lane >> 4;

  int srow = t >> 3;
  int g = (t & 7) ^ ((t >> 3) & 7);
  const unsigned short* pa = A + (size_t)(m0 + srow) * lda + g * 8;
  const unsigned short* pb = B + (size_t)(n0 + srow) * ldb + g * 8;

  f32x4 acc[4][4] = {};

  for (int k0 = 0; k0 < K; k0 += 64) {
    __syncthreads();
#pragma unroll
    for (int i = 0; i < 4; i++) {
      GLOAD16(pa + (size_t)(32 * i) * lda + k0,
              (char*)As + (size_t)(i * 256 + wid * 64) * 16);
      GLOAD16(pb + (size_t)(32 * i) * ldb + k0,
              (char*)Bs + (size_t)(i * 256 + wid * 64) * 16);
    }
    __syncthreads();
#pragma unroll
    for (int ks = 0; ks < 2; ks++) {
      short8 af[4], bfr[4];
#pragma unroll
      for (int mi = 0; mi < 4; mi++) {
        int r = wm * 64 + mi * 16 + l15;
        int c = ((ks << 2) | l4) ^ (r & 7);
        af[mi] = *(const short8*)((const char*)As + r * 128 + c * 16);
      }
#pragma unroll
      for (int ni = 0; ni < 4; ni++) {
        int r = wn * 64 + ni * 16 + l15;
        int c = ((ks << 2) | l4) ^ (r & 7);
        bfr[ni] = *(const short8*)((const char*)Bs + r * 128 + c * 16);
      }
#pragma unroll
      for (int mi = 0; mi < 4; mi++)
#pragma unroll
        for (int ni = 0; ni < 4; ni++)
          acc[mi][ni] = __builtin_amdgcn_mfma_f32_16x16x32_bf16(
              af[mi], bfr[ni], acc[mi][ni], 0, 0, 0);
    }
  }

#pragma unroll
  for (int mi = 0; mi < 4; mi++)
#pragma unroll
    for (int ni = 0; ni < 4; ni++)
#pragma unroll
      for (int j = 0; j < 4; j++) {
        int row = m0 + wm * 64 + mi * 16 + l4 * 4 + j;
        int col = n0 + wn * 64 + ni * 16 + l15;
        C[(size_t)row * ldc + col] = f2bf(acc[mi][ni][j] * scale);
      }
}

// ---------- gemm_body: the r12/r14/r15-verified 256^2 GEMM core ---------
// MODE 1: bf16 out (val*scale)
// MODE 2: bf16 out, exp(val*scale); per-wave partial rowsums to
//         rs[(bn*4+wn)*rsp + row] (plain stores; r11: cross-XCD atomicAdd
//         ping-pong cost ~47us -- never atomics here)
// MODE 3: f32 out, val * rs[row]  (rs holds INVERSE rowsums)
// 256x256 tile, 8 waves (2M x 4N), BK=64, double-buffered LDS (128 KiB).
// Staging: prefetch next tile, counted vmcnt(8); vmcnt(0) only on last
// tile; two barriers per K-tile. Compute: 4 quadrant phases with
// asm-pinned ds_read_b128 + counted lgkmcnt(4), setprio around MFMA.
// 16x16x32 MFMA kept (r13: 32x32 fragment pattern 4-way conflicts here).
// LDS swizzle: 16B slot ^= (row&7); inverse applied on global source.
// Requires M%256==0, N%256==0, K%64==0, gridDim.x%8==0.
template <int MODE>
__device__ __forceinline__ void gemm_body(
    unsigned short (*As)[256 * 64], unsigned short (*Bs)[256 * 64],
    const unsigned short* __restrict__ A, int lda,
    const unsigned short* __restrict__ B, int ldb,
    void* __restrict__ Cb, int ldc,
    float* __restrict__ rs, size_t rsp,
    int nbn, int K, float scale) {
  // XCD-aware block swizzle (gridDim.x multiple of 8)
  unsigned bid = blockIdx.x;
  unsigned cpx = gridDim.x >> 3;
  unsigned swz = (bid & 7u) * cpx + (bid >> 3);
  int bm = (int)(swz / (unsigned)nbn);
  int bn = (int)(swz % (unsigned)nbn);
  int m0 = bm * 256, n0 = bn * 256;

  int t512 = threadIdx.x;
  int lane = t512 & 63, wid = t512 >> 6;
  int wm = wid >> 2, wn = wid & 3;           // 2 x 4 wave grid
  int l15 = lane & 15, l4 = lane >> 4;

  // staging: thread t handles 16B chunks at rows srow+{0,64,128,192};
  // LDS slot = t&7 (linear dest), global chunk = slot ^ (srow&7).
  int srow = t512 >> 3;
  int g = (t512 & 7) ^ ((t512 >> 3) & 7);
  const unsigned short* pa = A + (size_t)(m0 + srow) * lda + g * 8;
  const unsigned short* pb = B + (size_t)(n0 + srow) * ldb + g * 8;

  f32x4 acc[8][4] = {};

  const int NT = K >> 6;

#define STAGE(jj, buf)                                                    \
  do {                                                                    \
    int _k0 = (jj) << 6;                                                  \
    _Pragma("unroll") for (int i = 0; i < 4; i++)                         \
        GLOAD16(pa + (size_t)(i * 64) * lda + _k0,                        \
                (char*)As[buf] + i * 8192 + t512 * 16);                   \
    _Pragma("unroll") for (int i = 0; i < 4; i++)                         \
        GLOAD16(pb + (size_t)(i * 64) * ldb + _k0,                        \
                (char*)Bs[buf] + i * 8192 + t512 * 16);                   \
  } while (0)

  // per-ks slot columns and fragment base addresses (mi/ni-independent)
  unsigned c0 = ((unsigned)l4) ^ (unsigned)(l15 & 7);
  unsigned c1 = (4u | (unsigned)l4) ^ (unsigned)(l15 & 7);
  unsigned rowA = (unsigned)(wm * 128 + l15) * 128u;
  unsigned rowB = (unsigned)(wn * 64 + l15) * 128u;

  // prologue: stage tile 0 into buffer 0
  STAGE(0, 0);

  for (int j = 0; j < NT; ++j) {
    int cur = j & 1;
    // pin iteration j-1's body before the stage below
    __builtin_amdgcn_sched_barrier(0);
    // barrier A: all waves done with buf[cur^1] (tile j-1)
    __builtin_amdgcn_s_barrier();
    if (j + 1 < NT) {
      STAGE(j + 1, cur ^ 1);
      // wait ONLY for tile j's 8 loads; the 8 just issued stay in flight
      asm volatile("s_waitcnt vmcnt(8)" ::: "memory");
    } else {
      asm volatile("s_waitcnt vmcnt(0)" ::: "memory");
    }
    // barrier B: every wave's tile-j loads have landed
    __builtin_amdgcn_s_barrier();

    unsigned baseA = (unsigned)(uintptr_t)(
        (__attribute__((address_space(3))) char*)(&As[cur][0]));
    unsigned baseB = (unsigned)(uintptr_t)(
        (__attribute__((address_space(3))) char*)(&Bs[cur][0]));
    unsigned aA0 = baseA + rowA + c0 * 16, aA1 = baseA + rowA + c1 * 16;
    unsigned aB0 = baseB + rowB + c0 * 16, aB1 = baseB + rowB + c1 * 16;

    short8 afq[2][2][2];  // [quadrant parity][m2][ks]
    short8 bfv[4][2];

    // issue quadrant 0 (4 reads) then all B (8 reads): outstanding = 12
    DSR(afq[0][0][0], aA0, 0);
    DSR(afq[0][0][1], aA1, 0);
    DSR(afq[0][1][0], aA0, 2048);
    DSR(afq[0][1][1], aA1, 2048);
#pragma unroll
    for (int ni = 0; ni < 4; ni++) {
      DSR(bfv[ni][0], aB0, ni * 2048);
      DSR(bfv[ni][1], aB1, ni * 2048);
    }

#pragma unroll
    for (int p = 0; p < 4; ++p) {
      if (p < 3) {
        const int mi0 = (p + 1) * 2;
        DSR(afq[(p + 1) & 1][0][0], aA0, mi0 * 2048);
        DSR(afq[(p + 1) & 1][0][1], aA1, mi0 * 2048);
        DSR(afq[(p + 1) & 1][1][0], aA0, (mi0 + 1) * 2048);
        DSR(afq[(p + 1) & 1][1][1], aA1, (mi0 + 1) * 2048);
        // drain everything except the 4 just issued
        asm volatile("s_waitcnt lgkmcnt(4)" ::: "memory");
      } else {
        asm volatile("s_waitcnt lgkmcnt(0)" ::: "memory");
      }
      __builtin_amdgcn_sched_barrier(0);  // rule #18 fence
      __builtin_amdgcn_s_setprio(1);
#pragma unroll
      for (int ks = 0; ks < 2; ks++)
#pragma unroll
        for (int m2 = 0; m2 < 2; m2++) {
          int mi = p * 2 + m2;
#pragma unroll
          for (int ni = 0; ni < 4; ni++)
            acc[mi][ni] = __builtin_amdgcn_mfma_f32_16x16x32_bf16(
                afq[p & 1][m2][ks], bfv[ni][ks], acc[mi][ni], 0, 0, 0);
        }
      __builtin_amdgcn_s_setprio(0);
      __builtin_amdgcn_sched_barrier(0);  // keep MFMA cluster in place
    }
  }
#undef STAGE

  // epilogue; row = m0 + wm*128 + mi*16 + l4*4 + jj, col = n0 + wn*64 + ni*16 + l15
  if constexpr (MODE == 2) {
    float sums[8][4];
#pragma unroll
    for (int mi = 0; mi < 8; mi++)
#pragma unroll
      for (int jj = 0; jj < 4; jj++) sums[mi][jj] = 0.f;
#pragma unroll
    for (int mi = 0; mi < 8; mi++)
#pragma unroll
      for (int ni = 0; ni < 4; ni++)
#pragma unroll
        for (int jj = 0; jj < 4; jj++) {
          int row = m0 + wm * 128 + mi * 16 + l4 * 4 + jj;
          int col = n0 + wn * 64 + ni * 16 + l15;
          float e = __expf(acc[mi][ni][jj] * scale);
          sums[mi][jj] += e;
          ((unsigned short*)Cb)[(size_t)row * ldc + col] = f2bf(e);
        }
    // per-wave partial: reduce 16 col-lanes, ONE plain store per row group
    size_t pslot = (size_t)(bn * 4 + wn) * rsp;
#pragma unroll
    for (int mi = 0; mi < 8; mi++)
#pragma unroll
      for (int jj = 0; jj < 4; jj++) {
        float s = sums[mi][jj];
        s += __shfl_xor(s, 1);
        s += __shfl_xor(s, 2);
        s += __shfl_xor(s, 4);
        s += __shfl_xor(s, 8);
        if (l15 == 0) {
          int row = m0 + wm * 128 + mi * 16 + l4 * 4 + jj;
          rs[pslot + row] = s;
        }
      }
  } else {
#pragma unroll
    for (int mi = 0; mi < 8; mi++) {
      float inv[4];
      if constexpr (MODE == 3) {
#pragma unroll
        for (int jj = 0; jj < 4; jj++) {
          int row = m0 + wm * 128 + mi * 16 + l4 * 4 + jj;
          inv[jj] = rs[row];  // already inverted by reduce_rsum
        }
      }
#pragma unroll
      for (int ni = 0; ni < 4; ni++)
#pragma unroll
        for (int jj = 0; jj < 4; jj++) {
          int row = m0 + wm * 128 + mi * 16 + l4 * 4 + jj;
          int col = n0 + wn * 64 + ni * 16 + l15;
          float val = acc[mi][ni][jj];
          if constexpr (MODE == 1)
            ((unsigned short*)Cb)[(size_t)row * ldc + col] = f2bf(val * scale);
          else
            ((float*)Cb)[(size_t)row * ldc + col] = val * inv[jj];
        }
    }
  }
}

// batched wrapper (blockIdx.y = batch) -- reproduces r15's kernel exactly
template <int MODE>
__global__ __launch_bounds__(512, 2) void gemm_bt256(
    const unsigned short* __restrict__ A, int lda, size_t asb,
    const unsigned short* __restrict__ B, int ldb, size_t bsb,
    void* __restrict__ C, int ldc, size_t csb,
    float* __restrict__ rs, int rss, size_t rsp,
    int nbn, int K, float scale) {
  __shared__ unsigned short As[2][256 * 64];
  __shared__ unsigned short Bs[2][256 * 64];
  gemm_body<MODE>(As, Bs,
                  A + (size_t)blockIdx.y * asb, lda,
                  B + (size_t)blockIdx.y * bsb, ldb,
                  (char*)C + (size_t)blockIdx.y * csb * (MODE == 3 ? 4 : 2),
                  ldc, rs + (size_t)blockIdx.y * rss, rsp, nbn, K, scale);
}

// dual-job wrapper: blockIdx.y==0 -> job0, ==1 -> job1 (both MODE 1, same K)
__global__ __launch_bounds__(512, 2) void gemm_dual(
    const unsigned short* __restrict__ A0, int lda0,
    const unsigned short* __restrict__ B0, int ldb0,
    void* __restrict__ C0, int ldc0, int nbn0,
    const unsigned short* __restrict__ A1, int lda1,
    const unsigned short* __restrict__ B1, int ldb1,
    void* __restrict__ C1, int ldc1, int nbn1, int K) {
  __shared__ unsigned short As[2][256 * 64];
  __shared__ unsigned short Bs[2][256 * 64];
  if (blockIdx.y == 0)
    gemm_body<1>(As, Bs, A0, lda0, B0, ldb0, C0, ldc0, nullptr, 0, nbn0, K,
                 1.0f);
  else
    gemm_body<1>(As, Bs, A1, lda1, B1, ldb1, C1, ldc1, nullptr, 0, nbn1, K,
                 1.0f);
}

// ---------- launcher ----------
// Pipeline (associativity: scores = x (Wq^T Wk) x^T):
//   cvt_all: xb = bf16(x); wqT/wkT = bf16 transposes; wvb = bf16(Wv)
//   MT = gemm128(wkT, wqT)
//   dual: VT = Wv x^T  ||  xM = x M^T
//   P = exp(xM x^T * scale) + partial rowsums ; rinv = 1/rowsum
//   out = (P V) * rinv
extern "C" void kernel_launch(void* const* d_in, const int* in_sizes, int n_in,
                              void* d_out, int out_size, void* d_ws, size_t ws_size,
                              hipStream_t stream) {
  (void)in_sizes; (void)n_in; (void)out_size;
  const float* x  = (const float*)d_in[0];
  const float* Wq = (const float*)d_in[1];
  const float* Wk = (const float*)d_in[2];
  const float* Wv = (const float*)d_in[3];
  float* out = (float*)d_out;

  const int Bn = 4, S = 4096, D = 1024;
  const size_t MS = (size_t)Bn * S;  // 16384
  const float scale = 0.03125f;      // 1/sqrt(1024)

  // ---- workspace layout ----
  char* ws = (char*)d_ws;
  unsigned short* xb  = (unsigned short*)ws; ws += MS * D * 2;   // 32 MiB
  unsigned short* xMb = (unsigned short*)ws; ws += MS * D * 2;   // 32 MiB
  unsigned short* VTb = (unsigned short*)ws; ws += MS * D * 2;   // 32 MiB
  unsigned short* Sreg = (unsigned short*)ws;
  const size_t s4_bytes = (size_t)Bn * S * S * 2;   // 128 MiB
  const size_t s1_bytes = (size_t)S * S * 2;        // 32 MiB
  size_t head = (size_t)(ws - (char*)d_ws);
  bool batched = ws_size >= head + s4_bytes + 16u * 1024 * 1024;
  ws += batched ? s4_bytes : s1_bytes;
  unsigned short* wqT = (unsigned short*)ws; ws += (size_t)D * D * 2;  // 2 MiB
  unsigned short* wkT = (unsigned short*)ws; ws += (size_t)D * D * 2;
  unsigned short* MTb = (unsigned short*)ws; ws += (size_t)D * D * 2;
  unsigned short* wvb = (unsigned short*)ws; ws += (size_t)D * D * 2;
  float* rpart = (float*)ws; ws += 64 * MS * sizeof(float);            // 4 MiB
  float* rinv  = (float*)ws;                                           // 64 KiB

  // merged conversion front-end (x, Wq/Wk transposes, Wv)
  cvt_all<<<9216, 256, 0, stream>>>(x, xb, Wq, Wk, wqT, wkT, Wv, wvb);

  // MT[j,i] = sum_o Wk[o,j]Wq[o,i]  (M=N=1024, K=1024; 64 blocks)
  gemm128<<<64, 256, 0, stream>>>(wkT, D, wqT, D, MTb, D, 8, D, 1.0f);

  // dual: VT = Wv @ x^T (1024 x 16384) || xM = x @ M^T (16384 x 1024)
  gemm_dual<<<dim3(256, 2), 512, 0, stream>>>(
      wvb, D, xb, D, VTb, (int)MS, 64,
      xb, D, MTb, D, xMb, D, 4, D);

  if (batched) {
    // P[b] = exp(xM_b x_b^T * scale); partial rowsums -> rpart
    gemm_bt256<2><<<dim3(256, Bn), 512, 0, stream>>>(
        xMb, D, (size_t)S * D,
        xb, D, (size_t)S * D,
        Sreg, S, (size_t)S * S, rpart, S, MS, 16, D, scale);
    // inverse rowsums
    reduce_rsum<<<(int)(MS / 256), 256, 0, stream>>>(rpart, rinv, MS, (int)MS);
    // out[b] = (P_b @ V_b) * rinv  (M=4096, N=1024, K=4096)
    gemm_bt256<3><<<dim3(64, Bn), 512, 0, stream>>>(
        Sreg, S, (size_t)S * S,
        VTb, (int)MS, (size_t)S,
        out, D, (size_t)S * D, rinv, S, 0, 4, S, 1.0f);
  } else {
    for (int b = 0; b < Bn; b++) {
      gemm_bt256<2><<<dim3(256, 1), 512, 0, stream>>>(
          xMb + (size_t)b * S * D, D, 0,
          xb + (size_t)b * S * D, D, 0,
          Sreg, S, 0, rpart + (size_t)b * S, 0, MS, 16, D, scale);
      reduce_rsum<<<S / 256, 256, 0, stream>>>(
          rpart + (size_t)b * S, rinv + (size_t)b * S, MS, S);
      gemm_bt256<3><<<dim3(64, 1), 512, 0, stream>>>(
          Sreg, S, 0, VTb + (size_t)b * S, (int)MS, 0,
          out + (size_t)b * S * D, D, 0, rinv + (size_t)b * S, 0, 0,
          4, S, 1.0f);
    }
  }
}

// Round 17
// 398.272 us; speedup vs baseline: 1.1792x; 1.0067x over previous
//
#include <hip/hip_runtime.h>
#include <cstdint>
#include <cstddef>

typedef __attribute__((ext_vector_type(8))) short short8;
typedef __attribute__((ext_vector_type(4))) float f32x4;

// ---------- helpers ----------
__device__ __forceinline__ unsigned short f2bf(float x) {
  union { float f; unsigned u; } v; v.f = x;
  unsigned r = (v.u + 0x7FFFu + ((v.u >> 16) & 1u)) >> 16;
  return (unsigned short)r;
}

#define GLOAD16(g, l)                                                    \
  __builtin_amdgcn_global_load_lds(                                      \
      (const __attribute__((address_space(1))) unsigned int*)(g),        \
      (__attribute__((address_space(3))) unsigned int*)(l), 16, 0, 0)

// inline-asm ds_read_b128: order-pinned so counted lgkmcnt is sound.
#define DSR(dst, addrv, imm)                                             \
  asm volatile("ds_read_b128 %0, %1 offset:%c2"                          \
               : "=&v"(dst) : "v"(addrv), "i"(imm))

// ---------- merged conversion front-end (one launch) ----------
// blocks [0,8192)    : cvt f32->bf16 of x        (16384x1024)
// blocks [8192,8704) : transpose+cvt Wq/Wk -> wqT/wkT (64x64 LDS tiles)
// blocks [8704,9216) : cvt f32->bf16 of Wv       (1024x1024)
__global__ __launch_bounds__(256) void cvt_all(
    const float* __restrict__ x, unsigned short* __restrict__ xb,
    const float* __restrict__ wq, const float* __restrict__ wk,
    unsigned short* __restrict__ wqT, unsigned short* __restrict__ wkT,
    const float* __restrict__ wv, unsigned short* __restrict__ wvb) {
  __shared__ float tile[64][65];
  int b = blockIdx.x;
  int t = threadIdx.x;
  if (b < 8192) {
    long i = ((long)b * 256 + t) * 8;
    const float4* p = (const float4*)(x + i);
    float4 a = p[0], c = p[1];
    short8 r;
    r[0] = (short)f2bf(a.x); r[1] = (short)f2bf(a.y);
    r[2] = (short)f2bf(a.z); r[3] = (short)f2bf(a.w);
    r[4] = (short)f2bf(c.x); r[5] = (short)f2bf(c.y);
    r[6] = (short)f2bf(c.z); r[7] = (short)f2bf(c.w);
    *(short8*)(xb + i) = r;
  } else if (b < 8704) {
    int tb = b - 8192;
    const float* in = (tb & 256) ? wk : wq;
    unsigned short* out = (tb & 256) ? wkT : wqT;
    int tb2 = tb & 255;
    int O0 = (tb2 >> 4) * 64;  // input row block (o)
    int I0 = (tb2 & 15) * 64;  // input col block (i)
    int r0 = t >> 6, c = t & 63;
#pragma unroll
    for (int r = 0; r < 16; r++) {
      int row = r * 4 + r0;
      tile[row][c] = in[(size_t)(O0 + row) * 1024 + I0 + c];
    }
    __syncthreads();
#pragma unroll
    for (int r = 0; r < 16; r++) {
      int irow = r * 4 + r0;
      out[(size_t)(I0 + irow) * 1024 + O0 + c] = f2bf(tile[c][irow]);
    }
  } else {
    long i = ((long)(b - 8704) * 256 + t) * 8;
    const float4* p = (const float4*)(wv + i);
    float4 a = p[0], c = p[1];
    short8 r;
    r[0] = (short)f2bf(a.x); r[1] = (short)f2bf(a.y);
    r[2] = (short)f2bf(a.z); r[3] = (short)f2bf(a.w);
    r[4] = (short)f2bf(c.x); r[5] = (short)f2bf(c.y);
    r[6] = (short)f2bf(c.z); r[7] = (short)f2bf(c.w);
    *(short8*)(wvb + i) = r;
  }
}

// sum 64 partials per row, store INVERSE (PV epilogue multiplies)
__global__ __launch_bounds__(256) void reduce_rsum(
    const float* __restrict__ part, float* __restrict__ outr,
    size_t stride, int n) {
  int i = blockIdx.x * 256 + threadIdx.x;
  if (i >= n) return;
  float s = 0.f;
#pragma unroll
  for (int p = 0; p < 64; p++) s += part[(size_t)p * stride + i];
  outr[i] = 1.0f / s;
}

// ---------- gemm128: C[m,n] = bf16( scale * sum_k A[m,k]*B[n,k] ) -------
// r1/r2-verified 128x128 tile, 4 waves, BK=64. Used for the tiny
// M^T weight GEMM (64 blocks) where the 256^2 kernel would waste a round.
__global__ __launch_bounds__(256) void gemm128(
    const unsigned short* __restrict__ A, int lda,
    const unsigned short* __restrict__ B, int ldb,
    unsigned short* __restrict__ C, int ldc,
    int nbn, int K, float scale) {
  __shared__ unsigned short As[128 * 64];
  __shared__ unsigned short Bs[128 * 64];

  unsigned bid = blockIdx.x;
  unsigned cpx = gridDim.x >> 3;
  unsigned swz = (bid & 7u) * cpx + (bid >> 3);
  int bm = (int)(swz / (unsigned)nbn);
  int bn = (int)(swz % (unsigned)nbn);
  int m0 = bm * 128, n0 = bn * 128;

  int t = threadIdx.x;
  int lane = t & 63, wid = t >> 6;
  int wm = wid >> 1, wn = wid & 1;
  int l15 = lane & 15, l4 = lane >> 4;

  int srow = t >> 3;
  int g = (t & 7) ^ ((t >> 3) & 7);
  const unsigned short* pa = A + (size_t)(m0 + srow) * lda + g * 8;
  const unsigned short* pb = B + (size_t)(n0 + srow) * ldb + g * 8;

  f32x4 acc[4][4] = {};

  for (int k0 = 0; k0 < K; k0 += 64) {
    __syncthreads();
#pragma unroll
    for (int i = 0; i < 4; i++) {
      GLOAD16(pa + (size_t)(32 * i) * lda + k0,
              (char*)As + (size_t)(i * 256 + wid * 64) * 16);
      GLOAD16(pb + (size_t)(32 * i) * ldb + k0,
              (char*)Bs + (size_t)(i * 256 + wid * 64) * 16);
    }
    __syncthreads();
#pragma unroll
    for (int ks = 0; ks < 2; ks++) {
      short8 af[4], bfr[4];
#pragma unroll
      for (int mi = 0; mi < 4; mi++) {
        int r = wm * 64 + mi * 16 + l15;
        int c = ((ks << 2) | l4) ^ (r & 7);
        af[mi] = *(const short8*)((const char*)As + r * 128 + c * 16);
      }
#pragma unroll
      for (int ni = 0; ni < 4; ni++) {
        int r = wn * 64 + ni * 16 + l15;
        int c = ((ks << 2) | l4) ^ (r & 7);
        bfr[ni] = *(const short8*)((const char*)Bs + r * 128 + c * 16);
      }
#pragma unroll
      for (int mi = 0; mi < 4; mi++)
#pragma unroll
        for (int ni = 0; ni < 4; ni++)
          acc[mi][ni] = __builtin_amdgcn_mfma_f32_16x16x32_bf16(
              af[mi], bfr[ni], acc[mi][ni], 0, 0, 0);
    }
  }

#pragma unroll
  for (int mi = 0; mi < 4; mi++)
#pragma unroll
    for (int ni = 0; ni < 4; ni++)
#pragma unroll
      for (int j = 0; j < 4; j++) {
        int row = m0 + wm * 64 + mi * 16 + l4 * 4 + j;
        int col = n0 + wn * 64 + ni * 16 + l15;
        C[(size_t)row * ldc + col] = f2bf(acc[mi][ni][j] * scale);
      }
}

// ---------- gemm_body: the r12/r14/r15/r16-verified 256^2 GEMM core -----
// MODE 1: bf16 out (val*scale)
// MODE 2: bf16 out, exp(val*scale); per-wave partial rowsums to
//         rs[(bn*4+wn)*rsp + row] (plain stores; r11: cross-XCD atomicAdd
//         ping-pong cost ~47us -- never atomics here)
// MODE 3: f32 out, val * rs[row]  (rs holds INVERSE rowsums)
// stile=0: verified XCD chunk map. stile=1 (requires gridDim.x==256,
// 16x16 block grid): each XCD's 32 co-resident blocks form a 4bm x 8bn
// rectangle -> per-XCD L2 working set 9MB -> 6MB (r17: scores over-fetch
// was 2.3x; B-panels thrash the 4MB XCD L2 under the strip map).
// 256x256 tile, 8 waves (2M x 4N), BK=64, double-buffered LDS (128 KiB).
// Staging: prefetch next tile, counted vmcnt(8); vmcnt(0) only on last
// tile; two barriers per K-tile. Compute: 4 quadrant phases with
// asm-pinned ds_read_b128 + counted lgkmcnt(4), setprio around MFMA.
// 16x16x32 MFMA kept (r13: 32x32 fragment pattern 4-way conflicts here).
// LDS swizzle: 16B slot ^= (row&7); inverse applied on global source.
// Requires M%256==0, N%256==0, K%64==0, gridDim.x%8==0.
template <int MODE>
__device__ __forceinline__ void gemm_body(
    unsigned short (*As)[256 * 64], unsigned short (*Bs)[256 * 64],
    const unsigned short* __restrict__ A, int lda,
    const unsigned short* __restrict__ B, int ldb,
    void* __restrict__ Cb, int ldc,
    float* __restrict__ rs, size_t rsp,
    int nbn, int K, float scale, int stile) {
  unsigned bid = blockIdx.x;
  int bm, bn;
  if (stile) {
    // 4x8 supertile per XCD (bijective: rectangles tile the 16x16 grid)
    unsigned xcd = bid & 7u, idx = bid >> 3;
    bm = (int)((xcd >> 1) * 4 + (idx & 3));
    bn = (int)((xcd & 1) * 8 + (idx >> 2));
  } else {
    unsigned cpx = gridDim.x >> 3;
    unsigned swz = (bid & 7u) * cpx + (bid >> 3);
    bm = (int)(swz / (unsigned)nbn);
    bn = (int)(swz % (unsigned)nbn);
  }
  int m0 = bm * 256, n0 = bn * 256;

  int t512 = threadIdx.x;
  int lane = t512 & 63, wid = t512 >> 6;
  int wm = wid >> 2, wn = wid & 3;           // 2 x 4 wave grid
  int l15 = lane & 15, l4 = lane >> 4;

  // staging: thread t handles 16B chunks at rows srow+{0,64,128,192};
  // LDS slot = t&7 (linear dest), global chunk = slot ^ (srow&7).
  int srow = t512 >> 3;
  int g = (t512 & 7) ^ ((t512 >> 3) & 7);
  const unsigned short* pa = A + (size_t)(m0 + srow) * lda + g * 8;
  const unsigned short* pb = B + (size_t)(n0 + srow) * ldb + g * 8;

  f32x4 acc[8][4] = {};

  const int NT = K >> 6;

#define STAGE(jj, buf)                                                    \
  do {                                                                    \
    int _k0 = (jj) << 6;                                                  \
    _Pragma("unroll") for (int i = 0; i < 4; i++)                         \
        GLOAD16(pa + (size_t)(i * 64) * lda + _k0,                        \
                (char*)As[buf] + i * 8192 + t512 * 16);                   \
    _Pragma("unroll") for (int i = 0; i < 4; i++)                         \
        GLOAD16(pb + (size_t)(i * 64) * ldb + _k0,                        \
                (char*)Bs[buf] + i * 8192 + t512 * 16);                   \
  } while (0)

  // per-ks slot columns and fragment base addresses (mi/ni-independent)
  unsigned c0 = ((unsigned)l4) ^ (unsigned)(l15 & 7);
  unsigned c1 = (4u | (unsigned)l4) ^ (unsigned)(l15 & 7);
  unsigned rowA = (unsigned)(wm * 128 + l15) * 128u;
  unsigned rowB = (unsigned)(wn * 64 + l15) * 128u;

  // prologue: stage tile 0 into buffer 0
  STAGE(0, 0);

  for (int j = 0; j < NT; ++j) {
    int cur = j & 1;
    // pin iteration j-1's body before the stage below
    __builtin_amdgcn_sched_barrier(0);
    // barrier A: all waves done with buf[cur^1] (tile j-1)
    __builtin_amdgcn_s_barrier();
    if (j + 1 < NT) {
      STAGE(j + 1, cur ^ 1);
      // wait ONLY for tile j's 8 loads; the 8 just issued stay in flight
      asm volatile("s_waitcnt vmcnt(8)" ::: "memory");
    } else {
      asm volatile("s_waitcnt vmcnt(0)" ::: "memory");
    }
    // barrier B: every wave's tile-j loads have landed
    __builtin_amdgcn_s_barrier();

    unsigned baseA = (unsigned)(uintptr_t)(
        (__attribute__((address_space(3))) char*)(&As[cur][0]));
    unsigned baseB = (unsigned)(uintptr_t)(
        (__attribute__((address_space(3))) char*)(&Bs[cur][0]));
    unsigned aA0 = baseA + rowA + c0 * 16, aA1 = baseA + rowA + c1 * 16;
    unsigned aB0 = baseB + rowB + c0 * 16, aB1 = baseB + rowB + c1 * 16;

    short8 afq[2][2][2];  // [quadrant parity][m2][ks]
    short8 bfv[4][2];

    // issue quadrant 0 (4 reads) then all B (8 reads): outstanding = 12
    DSR(afq[0][0][0], aA0, 0);
    DSR(afq[0][0][1], aA1, 0);
    DSR(afq[0][1][0], aA0, 2048);
    DSR(afq[0][1][1], aA1, 2048);
#pragma unroll
    for (int ni = 0; ni < 4; ni++) {
      DSR(bfv[ni][0], aB0, ni * 2048);
      DSR(bfv[ni][1], aB1, ni * 2048);
    }

#pragma unroll
    for (int p = 0; p < 4; ++p) {
      if (p < 3) {
        const int mi0 = (p + 1) * 2;
        DSR(afq[(p + 1) & 1][0][0], aA0, mi0 * 2048);
        DSR(afq[(p + 1) & 1][0][1], aA1, mi0 * 2048);
        DSR(afq[(p + 1) & 1][1][0], aA0, (mi0 + 1) * 2048);
        DSR(afq[(p + 1) & 1][1][1], aA1, (mi0 + 1) * 2048);
        // drain everything except the 4 just issued
        asm volatile("s_waitcnt lgkmcnt(4)" ::: "memory");
      } else {
        asm volatile("s_waitcnt lgkmcnt(0)" ::: "memory");
      }
      __builtin_amdgcn_sched_barrier(0);  // rule #18 fence
      __builtin_amdgcn_s_setprio(1);
#pragma unroll
      for (int ks = 0; ks < 2; ks++)
#pragma unroll
        for (int m2 = 0; m2 < 2; m2++) {
          int mi = p * 2 + m2;
#pragma unroll
          for (int ni = 0; ni < 4; ni++)
            acc[mi][ni] = __builtin_amdgcn_mfma_f32_16x16x32_bf16(
                afq[p & 1][m2][ks], bfv[ni][ks], acc[mi][ni], 0, 0, 0);
        }
      __builtin_amdgcn_s_setprio(0);
      __builtin_amdgcn_sched_barrier(0);  // keep MFMA cluster in place
    }
  }
#undef STAGE

  // epilogue; row = m0 + wm*128 + mi*16 + l4*4 + jj, col = n0 + wn*64 + ni*16 + l15
  if constexpr (MODE == 2) {
    float sums[8][4];
#pragma unroll
    for (int mi = 0; mi < 8; mi++)
#pragma unroll
      for (int jj = 0; jj < 4; jj++) sums[mi][jj] = 0.f;
#pragma unroll
    for (int mi = 0; mi < 8; mi++)
#pragma unroll
      for (int ni = 0; ni < 4; ni++)
#pragma unroll
        for (int jj = 0; jj < 4; jj++) {
          int row = m0 + wm * 128 + mi * 16 + l4 * 4 + jj;
          int col = n0 + wn * 64 + ni * 16 + l15;
          float e = __expf(acc[mi][ni][jj] * scale);
          sums[mi][jj] += e;
          ((unsigned short*)Cb)[(size_t)row * ldc + col] = f2bf(e);
        }
    // per-wave partial: reduce 16 col-lanes, ONE plain store per row group
    size_t pslot = (size_t)(bn * 4 + wn) * rsp;
#pragma unroll
    for (int mi = 0; mi < 8; mi++)
#pragma unroll
      for (int jj = 0; jj < 4; jj++) {
        float s = sums[mi][jj];
        s += __shfl_xor(s, 1);
        s += __shfl_xor(s, 2);
        s += __shfl_xor(s, 4);
        s += __shfl_xor(s, 8);
        if (l15 == 0) {
          int row = m0 + wm * 128 + mi * 16 + l4 * 4 + jj;
          rs[pslot + row] = s;
        }
      }
  } else {
#pragma unroll
    for (int mi = 0; mi < 8; mi++) {
      float inv[4];
      if constexpr (MODE == 3) {
#pragma unroll
        for (int jj = 0; jj < 4; jj++) {
          int row = m0 + wm * 128 + mi * 16 + l4 * 4 + jj;
          inv[jj] = rs[row];  // already inverted by reduce_rsum
        }
      }
#pragma unroll
      for (int ni = 0; ni < 4; ni++)
#pragma unroll
        for (int jj = 0; jj < 4; jj++) {
          int row = m0 + wm * 128 + mi * 16 + l4 * 4 + jj;
          int col = n0 + wn * 64 + ni * 16 + l15;
          float val = acc[mi][ni][jj];
          if constexpr (MODE == 1)
            ((unsigned short*)Cb)[(size_t)row * ldc + col] = f2bf(val * scale);
          else
            ((float*)Cb)[(size_t)row * ldc + col] = val * inv[jj];
        }
    }
  }
}

// batched wrapper (blockIdx.y = batch)
template <int MODE, int STILE>
__global__ __launch_bounds__(512, 2) void gemm_bt256(
    const unsigned short* __restrict__ A, int lda, size_t asb,
    const unsigned short* __restrict__ B, int ldb, size_t bsb,
    void* __restrict__ C, int ldc, size_t csb,
    float* __restrict__ rs, int rss, size_t rsp,
    int nbn, int K, float scale) {
  __shared__ unsigned short As[2][256 * 64];
  __shared__ unsigned short Bs[2][256 * 64];
  gemm_body<MODE>(As, Bs,
                  A + (size_t)blockIdx.y * asb, lda,
                  B + (size_t)blockIdx.y * bsb, ldb,
                  (char*)C + (size_t)blockIdx.y * csb * (MODE == 3 ? 4 : 2),
                  ldc, rs + (size_t)blockIdx.y * rss, rsp, nbn, K, scale,
                  STILE);
}

// dual-job wrapper: blockIdx.y==0 -> job0, ==1 -> job1 (both MODE 1, same K)
__global__ __launch_bounds__(512, 2) void gemm_dual(
    const unsigned short* __restrict__ A0, int lda0,
    const unsigned short* __restrict__ B0, int ldb0,
    void* __restrict__ C0, int ldc0, int nbn0,
    const unsigned short* __restrict__ A1, int lda1,
    const unsigned short* __restrict__ B1, int ldb1,
    void* __restrict__ C1, int ldc1, int nbn1, int K) {
  __shared__ unsigned short As[2][256 * 64];
  __shared__ unsigned short Bs[2][256 * 64];
  if (blockIdx.y == 0)
    gemm_body<1>(As, Bs, A0, lda0, B0, ldb0, C0, ldc0, nullptr, 0, nbn0, K,
                 1.0f, 0);
  else
    gemm_body<1>(As, Bs, A1, lda1, B1, ldb1, C1, ldc1, nullptr, 0, nbn1, K,
                 1.0f, 0);
}

// ---------- launcher ----------
// Pipeline (associativity: scores = x (Wq^T Wk) x^T):
//   cvt_all: xb = bf16(x); wqT/wkT = bf16 transposes; wvb = bf16(Wv)
//   MT = gemm128(wkT, wqT)
//   dual: VT = Wv x^T  ||  xM = x M^T
//   P = exp(xM x^T * scale) + partial rowsums ; rinv = 1/rowsum
//   out = (P V) * rinv
extern "C" void kernel_launch(void* const* d_in, const int* in_sizes, int n_in,
                              void* d_out, int out_size, void* d_ws, size_t ws_size,
                              hipStream_t stream) {
  (void)in_sizes; (void)n_in; (void)out_size;
  const float* x  = (const float*)d_in[0];
  const float* Wq = (const float*)d_in[1];
  const float* Wk = (const float*)d_in[2];
  const float* Wv = (const float*)d_in[3];
  float* out = (float*)d_out;

  const int Bn = 4, S = 4096, D = 1024;
  const size_t MS = (size_t)Bn * S;  // 16384
  const float scale = 0.03125f;      // 1/sqrt(1024)

  // ---- workspace layout ----
  char* ws = (char*)d_ws;
  unsigned short* xb  = (unsigned short*)ws; ws += MS * D * 2;   // 32 MiB
  unsigned short* xMb = (unsigned short*)ws; ws += MS * D * 2;   // 32 MiB
  unsigned short* VTb = (unsigned short*)ws; ws += MS * D * 2;   // 32 MiB
  unsigned short* Sreg = (unsigned short*)ws;
  const size_t s4_bytes = (size_t)Bn * S * S * 2;   // 128 MiB
  const size_t s1_bytes = (size_t)S * S * 2;        // 32 MiB
  size_t head = (size_t)(ws - (char*)d_ws);
  bool batched = ws_size >= head + s4_bytes + 16u * 1024 * 1024;
  ws += batched ? s4_bytes : s1_bytes;
  unsigned short* wqT = (unsigned short*)ws; ws += (size_t)D * D * 2;  // 2 MiB
  unsigned short* wkT = (unsigned short*)ws; ws += (size_t)D * D * 2;
  unsigned short* MTb = (unsigned short*)ws; ws += (size_t)D * D * 2;
  unsigned short* wvb = (unsigned short*)ws; ws += (size_t)D * D * 2;
  float* rpart = (float*)ws; ws += 64 * MS * sizeof(float);            // 4 MiB
  float* rinv  = (float*)ws;                                           // 64 KiB

  // merged conversion front-end (x, Wq/Wk transposes, Wv)
  cvt_all<<<9216, 256, 0, stream>>>(x, xb, Wq, Wk, wqT, wkT, Wv, wvb);

  // MT[j,i] = sum_o Wk[o,j]Wq[o,i]  (M=N=1024, K=1024; 64 blocks)
  gemm128<<<64, 256, 0, stream>>>(wkT, D, wqT, D, MTb, D, 8, D, 1.0f);

  // dual: VT = Wv @ x^T (1024 x 16384) || xM = x @ M^T (16384 x 1024)
  gemm_dual<<<dim3(256, 2), 512, 0, stream>>>(
      wvb, D, xb, D, VTb, (int)MS, 64,
      xb, D, MTb, D, xMb, D, 4, D);

  if (batched) {
    // P[b] = exp(xM_b x_b^T * scale); partial rowsums -> rpart
    // STILE=1: 4x8 supertile per XCD (16x16 grid, 256 blocks/batch)
    gemm_bt256<2, 1><<<dim3(256, Bn), 512, 0, stream>>>(
        xMb, D, (size_t)S * D,
        xb, D, (size_t)S * D,
        Sreg, S, (size_t)S * S, rpart, S, MS, 16, D, scale);
    // inverse rowsums
    reduce_rsum<<<(int)(MS / 256), 256, 0, stream>>>(rpart, rinv, MS, (int)MS);
    // out[b] = (P_b @ V_b) * rinv  (M=4096, N=1024, K=4096)
    gemm_bt256<3, 0><<<dim3(64, Bn), 512, 0, stream>>>(
        Sreg, S, (size_t)S * S,
        VTb, (int)MS, (size_t)S,
        out, D, (size_t)S * D, rinv, S, 0, 4, S, 1.0f);
  } else {
    for (int b = 0; b < Bn; b++) {
      gemm_bt256<2, 1><<<dim3(256, 1), 512, 0, stream>>>(
          xMb + (size_t)b * S * D, D, 0,
          xb + (size_t)b * S * D, D, 0,
          Sreg, S, 0, rpart + (size_t)b * S, 0, MS, 16, D, scale);
      reduce_rsum<<<S / 256, 256, 0, stream>>>(
          rpart + (size_t)b * S, rinv + (size_t)b * S, MS, S);
      gemm_bt256<3, 0><<<dim3(64, 1), 512, 0, stream>>>(
          Sreg, S, 0, VTb + (size_t)b * S, (int)MS, 0,
          out + (size_t)b * S * D, D, 0, rinv + (size_t)b * S, 0, 0,
          4, S, 1.0f);
    }
  }
}

// Round 18
// 396.034 us; speedup vs baseline: 1.1858x; 1.0057x over previous
//
#include <hip/hip_runtime.h>
#include <cstdint>
#include <cstddef>

typedef __attribute__((ext_vector_type(8))) short short8;
typedef __attribute__((ext_vector_type(4))) short short4v;
typedef __attribute__((ext_vector_type(4))) float f32x4;

// ---------- helpers ----------
__device__ __forceinline__ unsigned short f2bf(float x) {
  union { float f; unsigned u; } v; v.f = x;
  unsigned r = (v.u + 0x7FFFu + ((v.u >> 16) & 1u)) >> 16;
  return (unsigned short)r;
}

#define GLOAD16(g, l)                                                    \
  __builtin_amdgcn_global_load_lds(                                      \
      (const __attribute__((address_space(1))) unsigned int*)(g),        \
      (__attribute__((address_space(3))) unsigned int*)(l), 16, 0, 0)

// inline-asm ds_read_b128: order-pinned so counted lgkmcnt is sound.
#define DSR(dst, addrv, imm)                                             \
  asm volatile("ds_read_b128 %0, %1 offset:%c2"                          \
               : "=&v"(dst) : "v"(addrv), "i"(imm))

// ---------- merged conversion front-end (one launch) ----------
// blocks [0,8192)    : cvt f32->bf16 of x        (16384x1024)
// blocks [8192,8704) : transpose+cvt Wq/Wk -> wqT/wkT (64x64 LDS tiles)
// blocks [8704,9216) : cvt f32->bf16 of Wv       (1024x1024)
__global__ __launch_bounds__(256) void cvt_all(
    const float* __restrict__ x, unsigned short* __restrict__ xb,
    const float* __restrict__ wq, const float* __restrict__ wk,
    unsigned short* __restrict__ wqT, unsigned short* __restrict__ wkT,
    const float* __restrict__ wv, unsigned short* __restrict__ wvb) {
  __shared__ float tile[64][65];
  int b = blockIdx.x;
  int t = threadIdx.x;
  if (b < 8192) {
    long i = ((long)b * 256 + t) * 8;
    const float4* p = (const float4*)(x + i);
    float4 a = p[0], c = p[1];
    short8 r;
    r[0] = (short)f2bf(a.x); r[1] = (short)f2bf(a.y);
    r[2] = (short)f2bf(a.z); r[3] = (short)f2bf(a.w);
    r[4] = (short)f2bf(c.x); r[5] = (short)f2bf(c.y);
    r[6] = (short)f2bf(c.z); r[7] = (short)f2bf(c.w);
    *(short8*)(xb + i) = r;
  } else if (b < 8704) {
    int tb = b - 8192;
    const float* in = (tb & 256) ? wk : wq;
    unsigned short* out = (tb & 256) ? wkT : wqT;
    int tb2 = tb & 255;
    int O0 = (tb2 >> 4) * 64;  // input row block (o)
    int I0 = (tb2 & 15) * 64;  // input col block (i)
    int r0 = t >> 6, c = t & 63;
#pragma unroll
    for (int r = 0; r < 16; r++) {
      int row = r * 4 + r0;
      tile[row][c] = in[(size_t)(O0 + row) * 1024 + I0 + c];
    }
    __syncthreads();
#pragma unroll
    for (int r = 0; r < 16; r++) {
      int irow = r * 4 + r0;
      out[(size_t)(I0 + irow) * 1024 + O0 + c] = f2bf(tile[c][irow]);
    }
  } else {
    long i = ((long)(b - 8704) * 256 + t) * 8;
    const float4* p = (const float4*)(wv + i);
    float4 a = p[0], c = p[1];
    short8 r;
    r[0] = (short)f2bf(a.x); r[1] = (short)f2bf(a.y);
    r[2] = (short)f2bf(a.z); r[3] = (short)f2bf(a.w);
    r[4] = (short)f2bf(c.x); r[5] = (short)f2bf(c.y);
    r[6] = (short)f2bf(c.z); r[7] = (short)f2bf(c.w);
    *(short8*)(wvb + i) = r;
  }
}

// sum 64 partials per row, store INVERSE (PV epilogue multiplies)
__global__ __launch_bounds__(256) void reduce_rsum(
    const float* __restrict__ part, float* __restrict__ outr,
    size_t stride, int n) {
  int i = blockIdx.x * 256 + threadIdx.x;
  if (i >= n) return;
  float s = 0.f;
#pragma unroll
  for (int p = 0; p < 64; p++) s += part[(size_t)p * stride + i];
  outr[i] = 1.0f / s;
}

// ---------- mt_part: f32 K-chunk partials of MT = wkT x wqT^T ----------
// r18: the old 64-block gemm128 ran 16 SERIAL un-prefetched K-steps
// (~36us for a 2-GFLOP GEMM). Split K into 8 chunks of 128 (blockIdx.y):
// serial chain per block = 2 K-steps; 512 short blocks ~ 4-6us.
// Body = r1/r2-verified 128^2 tile, 4 waves, BK=64, same XOR swizzle.
__global__ __launch_bounds__(256) void mt_part(
    const unsigned short* __restrict__ A,   // wkT [1024][1024]
    const unsigned short* __restrict__ B,   // wqT [1024][1024]
    float* __restrict__ P) {                // [8][1024][1024] f32 partials
  __shared__ unsigned short As[128 * 64];
  __shared__ unsigned short Bs[128 * 64];
  const int lda = 1024, ldb = 1024;

  unsigned bid = blockIdx.x;
  unsigned cpx = gridDim.x >> 3;             // 64 blocks -> cpx=8
  unsigned swz = (bid & 7u) * cpx + (bid >> 3);
  int bm = (int)(swz >> 3);
  int bn = (int)(swz & 7u);
  int m0 = bm * 128, n0 = bn * 128;
  int kbase = (int)blockIdx.y << 7;          // 128-wide K window

  int t = threadIdx.x;
  int lane = t & 63, wid = t >> 6;
  int wm = wid >> 1, wn = wid & 1;
  int l15 = lane & 15, l4 = lane >> 4;

  int srow = t >> 3;
  int g = (t & 7) ^ ((t >> 3) & 7);
  const unsigned short* pa = A + (size_t)(m0 + srow) * lda + g * 8 + kbase;
  const unsigned short* pb = B + (size_t)(n0 + srow) * ldb + g * 8 + kbase;

  f32x4 acc[4][4] = {};

  for (int k0 = 0; k0 < 128; k0 += 64) {
    __syncthreads();
#pragma unroll
    for (int i = 0; i < 4; i++) {
      GLOAD16(pa + (size_t)(32 * i) * lda + k0,
              (char*)As + (size_t)(i * 256 + wid * 64) * 16);
      GLOAD16(pb + (size_t)(32 * i) * ldb + k0,
              (char*)Bs + (size_t)(i * 256 + wid * 64) * 16);
    }
    __syncthreads();
#pragma unroll
    for (int ks = 0; ks < 2; ks++) {
      short8 af[4], bfr[4];
#pragma unroll
      for (int mi = 0; mi < 4; mi++) {
        int r = wm * 64 + mi * 16 + l15;
        int c = ((ks << 2) | l4) ^ (r & 7);
        af[mi] = *(const short8*)((const char*)As + r * 128 + c * 16);
      }
#pragma unroll
      for (int ni = 0; ni < 4; ni++) {
        int r = wn * 64 + ni * 16 + l15;
        int c = ((ks << 2) | l4) ^ (r & 7);
        bfr[ni] = *(const short8*)((const char*)Bs + r * 128 + c * 16);
      }
#pragma unroll
      for (int mi = 0; mi < 4; mi++)
#pragma unroll
        for (int ni = 0; ni < 4; ni++)
          acc[mi][ni] = __builtin_amdgcn_mfma_f32_16x16x32_bf16(
              af[mi], bfr[ni], acc[mi][ni], 0, 0, 0);
    }
  }

  float* out = P + (size_t)blockIdx.y * 1048576;
#pragma unroll
  for (int mi = 0; mi < 4; mi++)
#pragma unroll
    for (int ni = 0; ni < 4; ni++)
#pragma unroll
      for (int j = 0; j < 4; j++) {
        int row = m0 + wm * 64 + mi * 16 + l4 * 4 + j;
        int col = n0 + wn * 64 + ni * 16 + l15;
        out[(size_t)row * 1024 + col] = acc[mi][ni][j];
      }
}

// sum the 8 f32 partials -> bf16 MTb (1M elems, 4/thread, 1024 blocks)
__global__ __launch_bounds__(256) void mt_reduce(
    const float* __restrict__ P, unsigned short* __restrict__ M) {
  size_t i = ((size_t)blockIdx.x * 256 + threadIdx.x) * 4;
  float4 s = *(const float4*)(P + i);
#pragma unroll
  for (int c = 1; c < 8; c++) {
    float4 v = *(const float4*)(P + (size_t)c * 1048576 + i);
    s.x += v.x; s.y += v.y; s.z += v.z; s.w += v.w;
  }
  short4v r;
  r[0] = (short)f2bf(s.x); r[1] = (short)f2bf(s.y);
  r[2] = (short)f2bf(s.z); r[3] = (short)f2bf(s.w);
  *(short4v*)(M + i) = r;
}

// ---------- gemm_body: the r12/r14/r15/r16-verified 256^2 GEMM core -----
// MODE 1: bf16 out (val*scale)
// MODE 2: bf16 out, exp(val*scale); per-wave partial rowsums to
//         rs[(bn*4+wn)*rsp + row] (plain stores; r11: cross-XCD atomicAdd
//         ping-pong cost ~47us -- never atomics here)
// MODE 3: f32 out, val * rs[row]  (rs holds INVERSE rowsums)
// stile=0: verified XCD chunk map. stile=1 (requires gridDim.x==256,
// 16x16 block grid): each XCD's 32 co-resident blocks form a 4bm x 8bn
// rectangle (r17: cut scores FETCH 147->98MB; time structural, kept for
// the HBM-traffic reduction).
// 256x256 tile, 8 waves (2M x 4N), BK=64, double-buffered LDS (128 KiB).
// Staging: prefetch next tile, counted vmcnt(8); vmcnt(0) only on last
// tile; two barriers per K-tile. Compute: 4 quadrant phases with
// asm-pinned ds_read_b128 + counted lgkmcnt(4), setprio around MFMA.
// 16x16x32 MFMA kept (r13: 32x32 fragment pattern 4-way conflicts here).
// LDS swizzle: 16B slot ^= (row&7); inverse applied on global source.
// Requires M%256==0, N%256==0, K%64==0, gridDim.x%8==0.
template <int MODE>
__device__ __forceinline__ void gemm_body(
    unsigned short (*As)[256 * 64], unsigned short (*Bs)[256 * 64],
    const unsigned short* __restrict__ A, int lda,
    const unsigned short* __restrict__ B, int ldb,
    void* __restrict__ Cb, int ldc,
    float* __restrict__ rs, size_t rsp,
    int nbn, int K, float scale, int stile) {
  unsigned bid = blockIdx.x;
  int bm, bn;
  if (stile) {
    // 4x8 supertile per XCD (bijective: rectangles tile the 16x16 grid)
    unsigned xcd = bid & 7u, idx = bid >> 3;
    bm = (int)((xcd >> 1) * 4 + (idx & 3));
    bn = (int)((xcd & 1) * 8 + (idx >> 2));
  } else {
    unsigned cpx = gridDim.x >> 3;
    unsigned swz = (bid & 7u) * cpx + (bid >> 3);
    bm = (int)(swz / (unsigned)nbn);
    bn = (int)(swz % (unsigned)nbn);
  }
  int m0 = bm * 256, n0 = bn * 256;

  int t512 = threadIdx.x;
  int lane = t512 & 63, wid = t512 >> 6;
  int wm = wid >> 2, wn = wid & 3;           // 2 x 4 wave grid
  int l15 = lane & 15, l4 = lane >> 4;

  // staging: thread t handles 16B chunks at rows srow+{0,64,128,192};
  // LDS slot = t&7 (linear dest), global chunk = slot ^ (srow&7).
  int srow = t512 >> 3;
  int g = (t512 & 7) ^ ((t512 >> 3) & 7);
  const unsigned short* pa = A + (size_t)(m0 + srow) * lda + g * 8;
  const unsigned short* pb = B + (size_t)(n0 + srow) * ldb + g * 8;

  f32x4 acc[8][4] = {};

  const int NT = K >> 6;

#define STAGE(jj, buf)                                                    \
  do {                                                                    \
    int _k0 = (jj) << 6;                                                  \
    _Pragma("unroll") for (int i = 0; i < 4; i++)                         \
        GLOAD16(pa + (size_t)(i * 64) * lda + _k0,                        \
                (char*)As[buf] + i * 8192 + t512 * 16);                   \
    _Pragma("unroll") for (int i = 0; i < 4; i++)                         \
        GLOAD16(pb + (size_t)(i * 64) * ldb + _k0,                        \
                (char*)Bs[buf] + i * 8192 + t512 * 16);                   \
  } while (0)

  // per-ks slot columns and fragment base addresses (mi/ni-independent)
  unsigned c0 = ((unsigned)l4) ^ (unsigned)(l15 & 7);
  unsigned c1 = (4u | (unsigned)l4) ^ (unsigned)(l15 & 7);
  unsigned rowA = (unsigned)(wm * 128 + l15) * 128u;
  unsigned rowB = (unsigned)(wn * 64 + l15) * 128u;

  // prologue: stage tile 0 into buffer 0
  STAGE(0, 0);

  for (int j = 0; j < NT; ++j) {
    int cur = j & 1;
    // pin iteration j-1's body before the stage below
    __builtin_amdgcn_sched_barrier(0);
    // barrier A: all waves done with buf[cur^1] (tile j-1)
    __builtin_amdgcn_s_barrier();
    if (j + 1 < NT) {
      STAGE(j + 1, cur ^ 1);
      // wait ONLY for tile j's 8 loads; the 8 just issued stay in flight
      asm volatile("s_waitcnt vmcnt(8)" ::: "memory");
    } else {
      asm volatile("s_waitcnt vmcnt(0)" ::: "memory");
    }
    // barrier B: every wave's tile-j loads have landed
    __builtin_amdgcn_s_barrier();

    unsigned baseA = (unsigned)(uintptr_t)(
        (__attribute__((address_space(3))) char*)(&As[cur][0]));
    unsigned baseB = (unsigned)(uintptr_t)(
        (__attribute__((address_space(3))) char*)(&Bs[cur][0]));
    unsigned aA0 = baseA + rowA + c0 * 16, aA1 = baseA + rowA + c1 * 16;
    unsigned aB0 = baseB + rowB + c0 * 16, aB1 = baseB + rowB + c1 * 16;

    short8 afq[2][2][2];  // [quadrant parity][m2][ks]
    short8 bfv[4][2];

    // issue quadrant 0 (4 reads) then all B (8 reads): outstanding = 12
    DSR(afq[0][0][0], aA0, 0);
    DSR(afq[0][0][1], aA1, 0);
    DSR(afq[0][1][0], aA0, 2048);
    DSR(afq[0][1][1], aA1, 2048);
#pragma unroll
    for (int ni = 0; ni < 4; ni++) {
      DSR(bfv[ni][0], aB0, ni * 2048);
      DSR(bfv[ni][1], aB1, ni * 2048);
    }

#pragma unroll
    for (int p = 0; p < 4; ++p) {
      if (p < 3) {
        const int mi0 = (p + 1) * 2;
        DSR(afq[(p + 1) & 1][0][0], aA0, mi0 * 2048);
        DSR(afq[(p + 1) & 1][0][1], aA1, mi0 * 2048);
        DSR(afq[(p + 1) & 1][1][0], aA0, (mi0 + 1) * 2048);
        DSR(afq[(p + 1) & 1][1][1], aA1, (mi0 + 1) * 2048);
        // drain everything except the 4 just issued
        asm volatile("s_waitcnt lgkmcnt(4)" ::: "memory");
      } else {
        asm volatile("s_waitcnt lgkmcnt(0)" ::: "memory");
      }
      __builtin_amdgcn_sched_barrier(0);  // rule #18 fence
      __builtin_amdgcn_s_setprio(1);
#pragma unroll
      for (int ks = 0; ks < 2; ks++)
#pragma unroll
        for (int m2 = 0; m2 < 2; m2++) {
          int mi = p * 2 + m2;
#pragma unroll
          for (int ni = 0; ni < 4; ni++)
            acc[mi][ni] = __builtin_amdgcn_mfma_f32_16x16x32_bf16(
                afq[p & 1][m2][ks], bfv[ni][ks], acc[mi][ni], 0, 0, 0);
        }
      __builtin_amdgcn_s_setprio(0);
      __builtin_amdgcn_sched_barrier(0);  // keep MFMA cluster in place
    }
  }
#undef STAGE

  // epilogue; row = m0 + wm*128 + mi*16 + l4*4 + jj, col = n0 + wn*64 + ni*16 + l15
  if constexpr (MODE == 2) {
    float sums[8][4];
#pragma unroll
    for (int mi = 0; mi < 8; mi++)
#pragma unroll
      for (int jj = 0; jj < 4; jj++) sums[mi][jj] = 0.f;
#pragma unroll
    for (int mi = 0; mi < 8; mi++)
#pragma unroll
      for (int ni = 0; ni < 4; ni++)
#pragma unroll
        for (int jj = 0; jj < 4; jj++) {
          int row = m0 + wm * 128 + mi * 16 + l4 * 4 + jj;
          int col = n0 + wn * 64 + ni * 16 + l15;
          float e = __expf(acc[mi][ni][jj] * scale);
          sums[mi][jj] += e;
          ((unsigned short*)Cb)[(size_t)row * ldc + col] = f2bf(e);
        }
    // per-wave partial: reduce 16 col-lanes, ONE plain store per row group
    size_t pslot = (size_t)(bn * 4 + wn) * rsp;
#pragma unroll
    for (int mi = 0; mi < 8; mi++)
#pragma unroll
      for (int jj = 0; jj < 4; jj++) {
        float s = sums[mi][jj];
        s += __shfl_xor(s, 1);
        s += __shfl_xor(s, 2);
        s += __shfl_xor(s, 4);
        s += __shfl_xor(s, 8);
        if (l15 == 0) {
          int row = m0 + wm * 128 + mi * 16 + l4 * 4 + jj;
          rs[pslot + row] = s;
        }
      }
  } else {
#pragma unroll
    for (int mi = 0; mi < 8; mi++) {
      float inv[4];
      if constexpr (MODE == 3) {
#pragma unroll
        for (int jj = 0; jj < 4; jj++) {
          int row = m0 + wm * 128 + mi * 16 + l4 * 4 + jj;
          inv[jj] = rs[row];  // already inverted by reduce_rsum
        }
      }
#pragma unroll
      for (int ni = 0; ni < 4; ni++)
#pragma unroll
        for (int jj = 0; jj < 4; jj++) {
          int row = m0 + wm * 128 + mi * 16 + l4 * 4 + jj;
          int col = n0 + wn * 64 + ni * 16 + l15;
          float val = acc[mi][ni][jj];
          if constexpr (MODE == 1)
            ((unsigned short*)Cb)[(size_t)row * ldc + col] = f2bf(val * scale);
          else
            ((float*)Cb)[(size_t)row * ldc + col] = val * inv[jj];
        }
    }
  }
}

// batched wrapper (blockIdx.y = batch)
template <int MODE, int STILE>
__global__ __launch_bounds__(512, 2) void gemm_bt256(
    const unsigned short* __restrict__ A, int lda, size_t asb,
    const unsigned short* __restrict__ B, int ldb, size_t bsb,
    void* __restrict__ C, int ldc, size_t csb,
    float* __restrict__ rs, int rss, size_t rsp,
    int nbn, int K, float scale) {
  __shared__ unsigned short As[2][256 * 64];
  __shared__ unsigned short Bs[2][256 * 64];
  gemm_body<MODE>(As, Bs,
                  A + (size_t)blockIdx.y * asb, lda,
                  B + (size_t)blockIdx.y * bsb, ldb,
                  (char*)C + (size_t)blockIdx.y * csb * (MODE == 3 ? 4 : 2),
                  ldc, rs + (size_t)blockIdx.y * rss, rsp, nbn, K, scale,
                  STILE);
}

// dual-job wrapper: blockIdx.y==0 -> job0, ==1 -> job1 (both MODE 1, same K)
__global__ __launch_bounds__(512, 2) void gemm_dual(
    const unsigned short* __restrict__ A0, int lda0,
    const unsigned short* __restrict__ B0, int ldb0,
    void* __restrict__ C0, int ldc0, int nbn0,
    const unsigned short* __restrict__ A1, int lda1,
    const unsigned short* __restrict__ B1, int ldb1,
    void* __restrict__ C1, int ldc1, int nbn1, int K) {
  __shared__ unsigned short As[2][256 * 64];
  __shared__ unsigned short Bs[2][256 * 64];
  if (blockIdx.y == 0)
    gemm_body<1>(As, Bs, A0, lda0, B0, ldb0, C0, ldc0, nullptr, 0, nbn0, K,
                 1.0f, 0);
  else
    gemm_body<1>(As, Bs, A1, lda1, B1, ldb1, C1, ldc1, nullptr, 0, nbn1, K,
                 1.0f, 0);
}

// ---------- launcher ----------
// Pipeline (associativity: scores = x (Wq^T Wk) x^T):
//   cvt_all: xb = bf16(x); wqT/wkT = bf16 transposes; wvb = bf16(Wv)
//   mt_part/mt_reduce: MT = wkT wqT^T  (8 K-chunk f32 partials + sum)
//   dual: VT = Wv x^T  ||  xM = x M^T
//   P = exp(xM x^T * scale) + partial rowsums ; rinv = 1/rowsum
//   out = (P V) * rinv
extern "C" void kernel_launch(void* const* d_in, const int* in_sizes, int n_in,
                              void* d_out, int out_size, void* d_ws, size_t ws_size,
                              hipStream_t stream) {
  (void)in_sizes; (void)n_in; (void)out_size;
  const float* x  = (const float*)d_in[0];
  const float* Wq = (const float*)d_in[1];
  const float* Wk = (const float*)d_in[2];
  const float* Wv = (const float*)d_in[3];
  float* out = (float*)d_out;

  const int Bn = 4, S = 4096, D = 1024;
  const size_t MS = (size_t)Bn * S;  // 16384
  const float scale = 0.03125f;      // 1/sqrt(1024)

  // ---- workspace layout ----
  char* ws = (char*)d_ws;
  unsigned short* xb  = (unsigned short*)ws; ws += MS * D * 2;   // 32 MiB
  unsigned short* xMb = (unsigned short*)ws; ws += MS * D * 2;   // 32 MiB
  unsigned short* VTb = (unsigned short*)ws; ws += MS * D * 2;   // 32 MiB
  unsigned short* Sreg = (unsigned short*)ws;
  const size_t s4_bytes = (size_t)Bn * S * S * 2;   // 128 MiB
  const size_t s1_bytes = (size_t)S * S * 2;        // 32 MiB
  size_t head = (size_t)(ws - (char*)d_ws);
  bool batched = ws_size >= head + s4_bytes + 16u * 1024 * 1024;
  ws += batched ? s4_bytes : s1_bytes;
  unsigned short* wqT = (unsigned short*)ws; ws += (size_t)D * D * 2;  // 2 MiB
  unsigned short* wkT = (unsigned short*)ws; ws += (size_t)D * D * 2;
  unsigned short* MTb = (unsigned short*)ws; ws += (size_t)D * D * 2;
  unsigned short* wvb = (unsigned short*)ws; ws += (size_t)D * D * 2;
  float* rpart = (float*)ws; ws += 64 * MS * sizeof(float);            // 4 MiB
  float* rinv  = (float*)ws;                                           // 64 KiB
  // mtp (8 x 1024x1024 f32 = 32 MiB) aliases Sreg: dead before any
  // scores write (mt_part/mt_reduce/dual all precede the scores dispatch).
  float* mtp = (float*)Sreg;

  // merged conversion front-end (x, Wq/Wk transposes, Wv)
  cvt_all<<<9216, 256, 0, stream>>>(x, xb, Wq, Wk, wqT, wkT, Wv, wvb);

  // MT[j,i] = sum_o Wk[o,j]Wq[o,i]: 8 K-chunk partials then reduce
  mt_part<<<dim3(64, 8), 256, 0, stream>>>(wkT, wqT, mtp);
  mt_reduce<<<1024, 256, 0, stream>>>(mtp, MTb);

  // dual: VT = Wv @ x^T (1024 x 16384) || xM = x @ M^T (16384 x 1024)
  gemm_dual<<<dim3(256, 2), 512, 0, stream>>>(
      wvb, D, xb, D, VTb, (int)MS, 64,
      xb, D, MTb, D, xMb, D, 4, D);

  if (batched) {
    // P[b] = exp(xM_b x_b^T * scale); partial rowsums -> rpart
    // STILE=1: 4x8 supertile per XCD (16x16 grid, 256 blocks/batch)
    gemm_bt256<2, 1><<<dim3(256, Bn), 512, 0, stream>>>(
        xMb, D, (size_t)S * D,
        xb, D, (size_t)S * D,
        Sreg, S, (size_t)S * S, rpart, S, MS, 16, D, scale);
    // inverse rowsums
    reduce_rsum<<<(int)(MS / 256), 256, 0, stream>>>(rpart, rinv, MS, (int)MS);
    // out[b] = (P_b @ V_b) * rinv  (M=4096, N=1024, K=4096)
    gemm_bt256<3, 0><<<dim3(64, Bn), 512, 0, stream>>>(
        Sreg, S, (size_t)S * S,
        VTb, (int)MS, (size_t)S,
        out, D, (size_t)S * D, rinv, S, 0, 4, S, 1.0f);
  } else {
    for (int b = 0; b < Bn; b++) {
      gemm_bt256<2, 1><<<dim3(256, 1), 512, 0, stream>>>(
          xMb + (size_t)b * S * D, D, 0,
          xb + (size_t)b * S * D, D, 0,
          Sreg, S, 0, rpart + (size_t)b * S, 0, MS, 16, D, scale);
      reduce_rsum<<<S / 256, 256, 0, stream>>>(
          rpart + (size_t)b * S, rinv + (size_t)b * S, MS, S);
      gemm_bt256<3, 0><<<dim3(64, 1), 512, 0, stream>>>(
          Sreg, S, 0, VTb + (size_t)b * S, (int)MS, 0,
          out + (size_t)b * S * D, D, 0, rinv + (size_t)b * S, 0, 0,
          4, S, 1.0f);
    }
  }
}

// Round 19
// 379.056 us; speedup vs baseline: 1.2389x; 1.0448x over previous
//
#include <hip/hip_runtime.h>
#include <cstdint>
#include <cstddef>

typedef __attribute__((ext_vector_type(8))) short short8;
typedef __attribute__((ext_vector_type(4))) short short4v;
typedef __attribute__((ext_vector_type(4))) float f32x4;

// ---------- helpers ----------
__device__ __forceinline__ unsigned short f2bf(float x) {
  union { float f; unsigned u; } v; v.f = x;
  unsigned r = (v.u + 0x7FFFu + ((v.u >> 16) & 1u)) >> 16;
  return (unsigned short)r;
}

#define GLOAD16(g, l)                                                    \
  __builtin_amdgcn_global_load_lds(                                      \
      (const __attribute__((address_space(1))) unsigned int*)(g),        \
      (__attribute__((address_space(3))) unsigned int*)(l), 16, 0, 0)

// inline-asm ds_read_b128: order-pinned so counted lgkmcnt is sound.
#define DSR(dst, addrv, imm)                                             \
  asm volatile("ds_read_b128 %0, %1 offset:%c2"                          \
               : "=&v"(dst) : "v"(addrv), "i"(imm))

// ---------- merged conversion front-end (one launch) ----------
// blocks [0,8192)    : cvt f32->bf16 of x        (16384x1024)
// blocks [8192,8704) : transpose+cvt Wq/Wk -> wqT/wkT (64x64 LDS tiles)
// blocks [8704,9216) : cvt f32->bf16 of Wv       (1024x1024)
__global__ __launch_bounds__(256) void cvt_all(
    const float* __restrict__ x, unsigned short* __restrict__ xb,
    const float* __restrict__ wq, const float* __restrict__ wk,
    unsigned short* __restrict__ wqT, unsigned short* __restrict__ wkT,
    const float* __restrict__ wv, unsigned short* __restrict__ wvb) {
  __shared__ float tile[64][65];
  int b = blockIdx.x;
  int t = threadIdx.x;
  if (b < 8192) {
    long i = ((long)b * 256 + t) * 8;
    const float4* p = (const float4*)(x + i);
    float4 a = p[0], c = p[1];
    short8 r;
    r[0] = (short)f2bf(a.x); r[1] = (short)f2bf(a.y);
    r[2] = (short)f2bf(a.z); r[3] = (short)f2bf(a.w);
    r[4] = (short)f2bf(c.x); r[5] = (short)f2bf(c.y);
    r[6] = (short)f2bf(c.z); r[7] = (short)f2bf(c.w);
    *(short8*)(xb + i) = r;
  } else if (b < 8704) {
    int tb = b - 8192;
    const float* in = (tb & 256) ? wk : wq;
    unsigned short* out = (tb & 256) ? wkT : wqT;
    int tb2 = tb & 255;
    int O0 = (tb2 >> 4) * 64;  // input row block (o)
    int I0 = (tb2 & 15) * 64;  // input col block (i)
    int r0 = t >> 6, c = t & 63;
#pragma unroll
    for (int r = 0; r < 16; r++) {
      int row = r * 4 + r0;
      tile[row][c] = in[(size_t)(O0 + row) * 1024 + I0 + c];
    }
    __syncthreads();
#pragma unroll
    for (int r = 0; r < 16; r++) {
      int irow = r * 4 + r0;
      out[(size_t)(I0 + irow) * 1024 + O0 + c] = f2bf(tile[c][irow]);
    }
  } else {
    long i = ((long)(b - 8704) * 256 + t) * 8;
    const float4* p = (const float4*)(wv + i);
    float4 a = p[0], c = p[1];
    short8 r;
    r[0] = (short)f2bf(a.x); r[1] = (short)f2bf(a.y);
    r[2] = (short)f2bf(a.z); r[3] = (short)f2bf(a.w);
    r[4] = (short)f2bf(c.x); r[5] = (short)f2bf(c.y);
    r[6] = (short)f2bf(c.z); r[7] = (short)f2bf(c.w);
    *(short8*)(wvb + i) = r;
  }
}

// ---------- mt_part: f32 K-chunk partials of MT = wkT x wqT^T ----------
// r18: split K into 8 chunks of 128 (blockIdx.y): serial chain per block
// = 2 K-steps. Body = r1/r2-verified 128^2 tile, 4 waves, BK=64.
__global__ __launch_bounds__(256) void mt_part(
    const unsigned short* __restrict__ A,   // wkT [1024][1024]
    const unsigned short* __restrict__ B,   // wqT [1024][1024]
    float* __restrict__ P) {                // [8][1024][1024] f32 partials
  __shared__ unsigned short As[128 * 64];
  __shared__ unsigned short Bs[128 * 64];
  const int lda = 1024, ldb = 1024;

  unsigned bid = blockIdx.x;
  unsigned cpx = gridDim.x >> 3;             // 64 blocks -> cpx=8
  unsigned swz = (bid & 7u) * cpx + (bid >> 3);
  int bm = (int)(swz >> 3);
  int bn = (int)(swz & 7u);
  int m0 = bm * 128, n0 = bn * 128;
  int kbase = (int)blockIdx.y << 7;          // 128-wide K window

  int t = threadIdx.x;
  int lane = t & 63, wid = t >> 6;
  int wm = wid >> 1, wn = wid & 1;
  int l15 = lane & 15, l4 = lane >> 4;

  int srow = t >> 3;
  int g = (t & 7) ^ ((t >> 3) & 7);
  const unsigned short* pa = A + (size_t)(m0 + srow) * lda + g * 8 + kbase;
  const unsigned short* pb = B + (size_t)(n0 + srow) * ldb + g * 8 + kbase;

  f32x4 acc[4][4] = {};

  for (int k0 = 0; k0 < 128; k0 += 64) {
    __syncthreads();
#pragma unroll
    for (int i = 0; i < 4; i++) {
      GLOAD16(pa + (size_t)(32 * i) * lda + k0,
              (char*)As + (size_t)(i * 256 + wid * 64) * 16);
      GLOAD16(pb + (size_t)(32 * i) * ldb + k0,
              (char*)Bs + (size_t)(i * 256 + wid * 64) * 16);
    }
    __syncthreads();
#pragma unroll
    for (int ks = 0; ks < 2; ks++) {
      short8 af[4], bfr[4];
#pragma unroll
      for (int mi = 0; mi < 4; mi++) {
        int r = wm * 64 + mi * 16 + l15;
        int c = ((ks << 2) | l4) ^ (r & 7);
        af[mi] = *(const short8*)((const char*)As + r * 128 + c * 16);
      }
#pragma unroll
      for (int ni = 0; ni < 4; ni++) {
        int r = wn * 64 + ni * 16 + l15;
        int c = ((ks << 2) | l4) ^ (r & 7);
        bfr[ni] = *(const short8*)((const char*)Bs + r * 128 + c * 16);
      }
#pragma unroll
      for (int mi = 0; mi < 4; mi++)
#pragma unroll
        for (int ni = 0; ni < 4; ni++)
          acc[mi][ni] = __builtin_amdgcn_mfma_f32_16x16x32_bf16(
              af[mi], bfr[ni], acc[mi][ni], 0, 0, 0);
    }
  }

  float* out = P + (size_t)blockIdx.y * 1048576;
#pragma unroll
  for (int mi = 0; mi < 4; mi++)
#pragma unroll
    for (int ni = 0; ni < 4; ni++)
#pragma unroll
      for (int j = 0; j < 4; j++) {
        int row = m0 + wm * 64 + mi * 16 + l4 * 4 + j;
        int col = n0 + wn * 64 + ni * 16 + l15;
        out[(size_t)row * 1024 + col] = acc[mi][ni][j];
      }
}

// sum the 8 f32 partials -> bf16 MTb (1M elems, 4/thread, 1024 blocks)
__global__ __launch_bounds__(256) void mt_reduce(
    const float* __restrict__ P, unsigned short* __restrict__ M) {
  size_t i = ((size_t)blockIdx.x * 256 + threadIdx.x) * 4;
  float4 s = *(const float4*)(P + i);
#pragma unroll
  for (int c = 1; c < 8; c++) {
    float4 v = *(const float4*)(P + (size_t)c * 1048576 + i);
    s.x += v.x; s.y += v.y; s.z += v.z; s.w += v.w;
  }
  short4v r;
  r[0] = (short)f2bf(s.x); r[1] = (short)f2bf(s.y);
  r[2] = (short)f2bf(s.z); r[3] = (short)f2bf(s.w);
  *(short4v*)(M + i) = r;
}

// ---------- gemm_body: the r12/r14/r15/r16-verified 256^2 GEMM core -----
// MODE 1: bf16 out (val*scale)
// MODE 2: bf16 out, exp(val*scale); per-wave partial rowsums to
//         rs[(bn*4+wn)*rsp + row] (plain stores; r11: cross-XCD atomicAdd
//         ping-pong cost ~47us -- never atomics here)
// MODE 3: f32 out, val * rinv[row]; r19: rinv computed IN-KERNEL from the
//         64 partials (2 threads/row x 32 slots + shfl + LDS stash) --
//         deletes the reduce_rsum launch and its gaps.
// stile=0: verified XCD chunk map. stile=1 (gridDim.x==256, 16x16 grid):
// 4bm x 8bn rectangle per XCD (r17: cut scores FETCH 147->98MB).
// 256x256 tile, 8 waves (2M x 4N), BK=64, double-buffered LDS (128 KiB).
// Staging: prefetch next tile, counted vmcnt(8); vmcnt(0) only on last
// tile; two barriers per K-tile. Compute: 4 quadrant phases with
// asm-pinned ds_read_b128 + counted lgkmcnt(4), setprio around MFMA.
// 16x16x32 MFMA kept (r13: 32x32 fragment pattern 4-way conflicts here).
// LDS swizzle: 16B slot ^= (row&7); inverse applied on global source.
// Requires M%256==0, N%256==0, K%64==0, gridDim.x%8==0.
template <int MODE>
__device__ __forceinline__ void gemm_body(
    unsigned short (*As)[256 * 64], unsigned short (*Bs)[256 * 64],
    float* rinv_s,
    const unsigned short* __restrict__ A, int lda,
    const unsigned short* __restrict__ B, int ldb,
    void* __restrict__ Cb, int ldc,
    float* __restrict__ rs, size_t rsp,
    int nbn, int K, float scale, int stile) {
  unsigned bid = blockIdx.x;
  int bm, bn;
  if (stile) {
    // 4x8 supertile per XCD (bijective: rectangles tile the 16x16 grid)
    unsigned xcd = bid & 7u, idx = bid >> 3;
    bm = (int)((xcd >> 1) * 4 + (idx & 3));
    bn = (int)((xcd & 1) * 8 + (idx >> 2));
  } else {
    unsigned cpx = gridDim.x >> 3;
    unsigned swz = (bid & 7u) * cpx + (bid >> 3);
    bm = (int)(swz / (unsigned)nbn);
    bn = (int)(swz % (unsigned)nbn);
  }
  int m0 = bm * 256, n0 = bn * 256;

  int t512 = threadIdx.x;
  int lane = t512 & 63, wid = t512 >> 6;
  int wm = wid >> 2, wn = wid & 3;           // 2 x 4 wave grid
  int l15 = lane & 15, l4 = lane >> 4;

  // r19 prologue (MODE 3): cooperative inverse-rowsum for this block's
  // 256 rows. 2 threads/row, 32 slots each over the 64 partial slabs
  // (rpart is 4 MiB, L2-resident); shfl_xor(1) pairs adjacent lanes.
  if constexpr (MODE == 3) {
    int row = t512 >> 1;
    int half = t512 & 1;
    const float* p = rs + (size_t)(half * 32) * rsp + (m0 + row);
    float s = 0.f;
#pragma unroll
    for (int k = 0; k < 32; k++) s += p[(size_t)k * rsp];
    s += __shfl_xor(s, 1);
    if (half == 0) rinv_s[row] = 1.0f / s;
    __syncthreads();
  }

  // staging: thread t handles 16B chunks at rows srow+{0,64,128,192};
  // LDS slot = t&7 (linear dest), global chunk = slot ^ (srow&7).
  int srow = t512 >> 3;
  int g = (t512 & 7) ^ ((t512 >> 3) & 7);
  const unsigned short* pa = A + (size_t)(m0 + srow) * lda + g * 8;
  const unsigned short* pb = B + (size_t)(n0 + srow) * ldb + g * 8;

  f32x4 acc[8][4] = {};

  const int NT = K >> 6;

#define STAGE(jj, buf)                                                    \
  do {                                                                    \
    int _k0 = (jj) << 6;                                                  \
    _Pragma("unroll") for (int i = 0; i < 4; i++)                         \
        GLOAD16(pa + (size_t)(i * 64) * lda + _k0,                        \
                (char*)As[buf] + i * 8192 + t512 * 16);                   \
    _Pragma("unroll") for (int i = 0; i < 4; i++)                         \
        GLOAD16(pb + (size_t)(i * 64) * ldb + _k0,                        \
                (char*)Bs[buf] + i * 8192 + t512 * 16);                   \
  } while (0)

  // per-ks slot columns and fragment base addresses (mi/ni-independent)
  unsigned c0 = ((unsigned)l4) ^ (unsigned)(l15 & 7);
  unsigned c1 = (4u | (unsigned)l4) ^ (unsigned)(l15 & 7);
  unsigned rowA = (unsigned)(wm * 128 + l15) * 128u;
  unsigned rowB = (unsigned)(wn * 64 + l15) * 128u;

  // prologue: stage tile 0 into buffer 0
  STAGE(0, 0);

  for (int j = 0; j < NT; ++j) {
    int cur = j & 1;
    // pin iteration j-1's body before the stage below
    __builtin_amdgcn_sched_barrier(0);
    // barrier A: all waves done with buf[cur^1] (tile j-1)
    __builtin_amdgcn_s_barrier();
    if (j + 1 < NT) {
      STAGE(j + 1, cur ^ 1);
      // wait ONLY for tile j's 8 loads; the 8 just issued stay in flight
      asm volatile("s_waitcnt vmcnt(8)" ::: "memory");
    } else {
      asm volatile("s_waitcnt vmcnt(0)" ::: "memory");
    }
    // barrier B: every wave's tile-j loads have landed
    __builtin_amdgcn_s_barrier();

    unsigned baseA = (unsigned)(uintptr_t)(
        (__attribute__((address_space(3))) char*)(&As[cur][0]));
    unsigned baseB = (unsigned)(uintptr_t)(
        (__attribute__((address_space(3))) char*)(&Bs[cur][0]));
    unsigned aA0 = baseA + rowA + c0 * 16, aA1 = baseA + rowA + c1 * 16;
    unsigned aB0 = baseB + rowB + c0 * 16, aB1 = baseB + rowB + c1 * 16;

    short8 afq[2][2][2];  // [quadrant parity][m2][ks]
    short8 bfv[4][2];

    // issue quadrant 0 (4 reads) then all B (8 reads): outstanding = 12
    DSR(afq[0][0][0], aA0, 0);
    DSR(afq[0][0][1], aA1, 0);
    DSR(afq[0][1][0], aA0, 2048);
    DSR(afq[0][1][1], aA1, 2048);
#pragma unroll
    for (int ni = 0; ni < 4; ni++) {
      DSR(bfv[ni][0], aB0, ni * 2048);
      DSR(bfv[ni][1], aB1, ni * 2048);
    }

#pragma unroll
    for (int p = 0; p < 4; ++p) {
      if (p < 3) {
        const int mi0 = (p + 1) * 2;
        DSR(afq[(p + 1) & 1][0][0], aA0, mi0 * 2048);
        DSR(afq[(p + 1) & 1][0][1], aA1, mi0 * 2048);
        DSR(afq[(p + 1) & 1][1][0], aA0, (mi0 + 1) * 2048);
        DSR(afq[(p + 1) & 1][1][1], aA1, (mi0 + 1) * 2048);
        // drain everything except the 4 just issued
        asm volatile("s_waitcnt lgkmcnt(4)" ::: "memory");
      } else {
        asm volatile("s_waitcnt lgkmcnt(0)" ::: "memory");
      }
      __builtin_amdgcn_sched_barrier(0);  // rule #18 fence
      __builtin_amdgcn_s_setprio(1);
#pragma unroll
      for (int ks = 0; ks < 2; ks++)
#pragma unroll
        for (int m2 = 0; m2 < 2; m2++) {
          int mi = p * 2 + m2;
#pragma unroll
          for (int ni = 0; ni < 4; ni++)
            acc[mi][ni] = __builtin_amdgcn_mfma_f32_16x16x32_bf16(
                afq[p & 1][m2][ks], bfv[ni][ks], acc[mi][ni], 0, 0, 0);
        }
      __builtin_amdgcn_s_setprio(0);
      __builtin_amdgcn_sched_barrier(0);  // keep MFMA cluster in place
    }
  }
#undef STAGE

  // epilogue; row = m0 + wm*128 + mi*16 + l4*4 + jj, col = n0 + wn*64 + ni*16 + l15
  if constexpr (MODE == 2) {
    float sums[8][4];
#pragma unroll
    for (int mi = 0; mi < 8; mi++)
#pragma unroll
      for (int jj = 0; jj < 4; jj++) sums[mi][jj] = 0.f;
#pragma unroll
    for (int mi = 0; mi < 8; mi++)
#pragma unroll
      for (int ni = 0; ni < 4; ni++)
#pragma unroll
        for (int jj = 0; jj < 4; jj++) {
          int row = m0 + wm * 128 + mi * 16 + l4 * 4 + jj;
          int col = n0 + wn * 64 + ni * 16 + l15;
          float e = __expf(acc[mi][ni][jj] * scale);
          sums[mi][jj] += e;
          ((unsigned short*)Cb)[(size_t)row * ldc + col] = f2bf(e);
        }
    // per-wave partial: reduce 16 col-lanes, ONE plain store per row group
    size_t pslot = (size_t)(bn * 4 + wn) * rsp;
#pragma unroll
    for (int mi = 0; mi < 8; mi++)
#pragma unroll
      for (int jj = 0; jj < 4; jj++) {
        float s = sums[mi][jj];
        s += __shfl_xor(s, 1);
        s += __shfl_xor(s, 2);
        s += __shfl_xor(s, 4);
        s += __shfl_xor(s, 8);
        if (l15 == 0) {
          int row = m0 + wm * 128 + mi * 16 + l4 * 4 + jj;
          rs[pslot + row] = s;
        }
      }
  } else {
#pragma unroll
    for (int mi = 0; mi < 8; mi++) {
      float inv[4];
      if constexpr (MODE == 3) {
#pragma unroll
        for (int jj = 0; jj < 4; jj++)
          inv[jj] = rinv_s[wm * 128 + mi * 16 + l4 * 4 + jj];
      }
#pragma unroll
      for (int ni = 0; ni < 4; ni++)
#pragma unroll
        for (int jj = 0; jj < 4; jj++) {
          int row = m0 + wm * 128 + mi * 16 + l4 * 4 + jj;
          int col = n0 + wn * 64 + ni * 16 + l15;
          float val = acc[mi][ni][jj];
          if constexpr (MODE == 1)
            ((unsigned short*)Cb)[(size_t)row * ldc + col] = f2bf(val * scale);
          else
            ((float*)Cb)[(size_t)row * ldc + col] = val * inv[jj];
        }
    }
  }
}

// batched wrapper (blockIdx.y = batch)
template <int MODE, int STILE>
__global__ __launch_bounds__(512, 2) void gemm_bt256(
    const unsigned short* __restrict__ A, int lda, size_t asb,
    const unsigned short* __restrict__ B, int ldb, size_t bsb,
    void* __restrict__ C, int ldc, size_t csb,
    float* __restrict__ rs, int rss, size_t rsp,
    int nbn, int K, float scale) {
  __shared__ unsigned short As[2][256 * 64];
  __shared__ unsigned short Bs[2][256 * 64];
  __shared__ float rsh[256];
  gemm_body<MODE>(As, Bs, rsh,
                  A + (size_t)blockIdx.y * asb, lda,
                  B + (size_t)blockIdx.y * bsb, ldb,
                  (char*)C + (size_t)blockIdx.y * csb * (MODE == 3 ? 4 : 2),
                  ldc, rs + (size_t)blockIdx.y * rss, rsp, nbn, K, scale,
                  STILE);
}

// dual-job wrapper: blockIdx.y==0 -> job0, ==1 -> job1 (both MODE 1, same K)
__global__ __launch_bounds__(512, 2) void gemm_dual(
    const unsigned short* __restrict__ A0, int lda0,
    const unsigned short* __restrict__ B0, int ldb0,
    void* __restrict__ C0, int ldc0, int nbn0,
    const unsigned short* __restrict__ A1, int lda1,
    const unsigned short* __restrict__ B1, int ldb1,
    void* __restrict__ C1, int ldc1, int nbn1, int K) {
  __shared__ unsigned short As[2][256 * 64];
  __shared__ unsigned short Bs[2][256 * 64];
  if (blockIdx.y == 0)
    gemm_body<1>(As, Bs, nullptr, A0, lda0, B0, ldb0, C0, ldc0, nullptr, 0,
                 nbn0, K, 1.0f, 0);
  else
    gemm_body<1>(As, Bs, nullptr, A1, lda1, B1, ldb1, C1, ldc1, nullptr, 0,
                 nbn1, K, 1.0f, 0);
}

// ---------- launcher ----------
// Pipeline (associativity: scores = x (Wq^T Wk) x^T):
//   cvt_all: xb = bf16(x); wqT/wkT = bf16 transposes; wvb = bf16(Wv)
//   mt_part/mt_reduce: MT = wkT wqT^T  (8 K-chunk f32 partials + sum)
//   dual: VT = Wv x^T  ||  xM = x M^T
//   P = exp(xM x^T * scale) + partial rowsums
//   out = (P V) * rinv   (rinv fused into the PV kernel's prologue, r19)
extern "C" void kernel_launch(void* const* d_in, const int* in_sizes, int n_in,
                              void* d_out, int out_size, void* d_ws, size_t ws_size,
                              hipStream_t stream) {
  (void)in_sizes; (void)n_in; (void)out_size;
  const float* x  = (const float*)d_in[0];
  const float* Wq = (const float*)d_in[1];
  const float* Wk = (const float*)d_in[2];
  const float* Wv = (const float*)d_in[3];
  float* out = (float*)d_out;

  const int Bn = 4, S = 4096, D = 1024;
  const size_t MS = (size_t)Bn * S;  // 16384
  const float scale = 0.03125f;      // 1/sqrt(1024)

  // ---- workspace layout ----
  char* ws = (char*)d_ws;
  unsigned short* xb  = (unsigned short*)ws; ws += MS * D * 2;   // 32 MiB
  unsigned short* xMb = (unsigned short*)ws; ws += MS * D * 2;   // 32 MiB
  unsigned short* VTb = (unsigned short*)ws; ws += MS * D * 2;   // 32 MiB
  unsigned short* Sreg = (unsigned short*)ws;
  const size_t s4_bytes = (size_t)Bn * S * S * 2;   // 128 MiB
  const size_t s1_bytes = (size_t)S * S * 2;        // 32 MiB
  size_t head = (size_t)(ws - (char*)d_ws);
  bool batched = ws_size >= head + s4_bytes + 16u * 1024 * 1024;
  ws += batched ? s4_bytes : s1_bytes;
  unsigned short* wqT = (unsigned short*)ws; ws += (size_t)D * D * 2;  // 2 MiB
  unsigned short* wkT = (unsigned short*)ws; ws += (size_t)D * D * 2;
  unsigned short* MTb = (unsigned short*)ws; ws += (size_t)D * D * 2;
  unsigned short* wvb = (unsigned short*)ws; ws += (size_t)D * D * 2;
  float* rpart = (float*)ws; ws += 64 * MS * sizeof(float);            // 4 MiB
  // mtp (8 x 1024x1024 f32 = 32 MiB) aliases Sreg: dead before any
  // scores write (mt_part/mt_reduce/dual all precede the scores dispatch).
  float* mtp = (float*)Sreg;

  // merged conversion front-end (x, Wq/Wk transposes, Wv)
  cvt_all<<<9216, 256, 0, stream>>>(x, xb, Wq, Wk, wqT, wkT, Wv, wvb);

  // MT[j,i] = sum_o Wk[o,j]Wq[o,i]: 8 K-chunk partials then reduce
  mt_part<<<dim3(64, 8), 256, 0, stream>>>(wkT, wqT, mtp);
  mt_reduce<<<1024, 256, 0, stream>>>(mtp, MTb);

  // dual: VT = Wv @ x^T (1024 x 16384) || xM = x @ M^T (16384 x 1024)
  gemm_dual<<<dim3(256, 2), 512, 0, stream>>>(
      wvb, D, xb, D, VTb, (int)MS, 64,
      xb, D, MTb, D, xMb, D, 4, D);

  if (batched) {
    // P[b] = exp(xM_b x_b^T * scale); partial rowsums -> rpart
    // STILE=1: 4x8 supertile per XCD (16x16 grid, 256 blocks/batch)
    gemm_bt256<2, 1><<<dim3(256, Bn), 512, 0, stream>>>(
        xMb, D, (size_t)S * D,
        xb, D, (size_t)S * D,
        Sreg, S, (size_t)S * S, rpart, S, MS, 16, D, scale);
    // out[b] = (P_b @ V_b) * rinv  (M=4096, N=1024, K=4096);
    // rinv computed in-kernel from rpart (r19 fusion)
    gemm_bt256<3, 0><<<dim3(64, Bn), 512, 0, stream>>>(
        Sreg, S, (size_t)S * S,
        VTb, (int)MS, (size_t)S,
        out, D, (size_t)S * D, rpart, S, MS, 4, S, 1.0f);
  } else {
    for (int b = 0; b < Bn; b++) {
      gemm_bt256<2, 1><<<dim3(256, 1), 512, 0, stream>>>(
          xMb + (size_t)b * S * D, D, 0,
          xb + (size_t)b * S * D, D, 0,
          Sreg, S, 0, rpart + (size_t)b * S, 0, MS, 16, D, scale);
      gemm_bt256<3, 0><<<dim3(64, 1), 512, 0, stream>>>(
          Sreg, S, 0, VTb + (size_t)b * S, (int)MS, 0,
          out + (size_t)b * S * D, D, 0, rpart + (size_t)b * S, 0, MS,
          4, S, 1.0f);
    }
  }
}